// Round 11
// baseline (174.888 us; speedup 1.0000x reference)
//
#include <hip/hip_runtime.h>
#include <hip/hip_bf16.h>

typedef __bf16 bf16x8 __attribute__((ext_vector_type(8)));
typedef float f32x4 __attribute__((ext_vector_type(4)));
typedef float f32x16 __attribute__((ext_vector_type(16)));
typedef short short8 __attribute__((ext_vector_type(8)));

#define MFMA16(a, b, c) __builtin_amdgcn_mfma_f32_16x16x32_bf16((a), (b), (c), 0, 0, 0)
#define MFMA32(a, b, c) __builtin_amdgcn_mfma_f32_32x32x16_bf16((a), (b), (c), 0, 0, 0)

static constexpr int S = 2048;
static constexpr int D = 512;
static constexpr int HD = 64;
static constexpr int KBLK = 64;
// q scale: 1/sqrt(HD) * log2(e), so softmax can use exp2
#define QSCALE 0.18033688011112042f

typedef __attribute__((address_space(1))) const unsigned int gu32;
typedef __attribute__((address_space(3))) unsigned int lu32;

__device__ __forceinline__ void gll16(const void* g, void* l) {
  __builtin_amdgcn_global_load_lds((gu32*)g, (lu32*)l, 16, 0, 0);
}

__device__ __forceinline__ unsigned short f2b(float f) {
  return __builtin_bit_cast(unsigned short, __float2bfloat16(f));
}
__device__ __forceinline__ float b2f(unsigned short u) {
  return __builtin_bit_cast(float, (unsigned)u << 16);
}

// ---------------- mask (int32 0/1) -> bitmask [B*S][S/64] u64 ----------------
__global__ void maskbits_kernel(const int* __restrict__ m, unsigned long long* __restrict__ bits) {
  int gid = blockIdx.x * 256 + threadIdx.x;
  int lane = threadIdx.x & 63;
  unsigned long long w = __ballot(m[gid] != 0);
  if (lane == 0) bits[gid >> 6] = w;
}

// ---------------- cast x (f32 -> bf16), 4 elems/thread ----------------
__global__ void cast_x_kernel(const float* __restrict__ x, unsigned short* __restrict__ xb) {
  int idx = blockIdx.x * 256 + threadIdx.x;
  float4 v = ((const float4*)x)[idx];
  ushort4 o;
  o.x = f2b(v.x); o.y = f2b(v.y); o.z = f2b(v.z); o.w = f2b(v.w);
  ((ushort4*)xb)[idx] = o;
}

// ------------- tiled transpose+cast of the 4 weight matrices -------------
__global__ void wtrans4_kernel(const float* __restrict__ wq, const float* __restrict__ wk,
                               const float* __restrict__ wv, const float* __restrict__ wo,
                               unsigned short* __restrict__ wqkvT, unsigned short* __restrict__ woT) {
  __shared__ float t[64][65];
  const int z = blockIdx.z;
  const float* w = (z == 0) ? wq : (z == 1) ? wk : (z == 2) ? wv : wo;
  unsigned short* dst = (z < 3) ? wqkvT + (size_t)z * 512 * 512 : woT;
  const int i0 = blockIdx.x * 64, o0 = blockIdx.y * 64;
  for (int it = 0; it < 16; ++it) {
    int idx = it * 256 + threadIdx.x;
    int ii = idx >> 6, oo = idx & 63;
    t[oo][ii] = w[(size_t)(i0 + ii) * 512 + o0 + oo];
  }
  __syncthreads();
  for (int it = 0; it < 16; ++it) {
    int idx = it * 256 + threadIdx.x;
    int oo = idx >> 6, ii = idx & 63;
    dst[(size_t)(o0 + oo) * 512 + i0 + ii] = f2b(t[oo][ii]);
  }
}

// ------------- GEMM: C = A[M][K] * Bt[N][K]^T, gll16-staged dbuf, 128x128 tile BK=32 -------------
// XCD-grouped linear grid: wgid -> (x=wgid&7, t=wgid>>3, n=t%12, m=(t/12)*8+x) so blocks sharing
// an A-panel run on one XCD (A fetched ~once per XCD; B is L2-resident).
// mode 0: f32 C row-major. mode 1: bf16 per-head scatter: q/k pre-rope [B,H,S,HD]; V TRANSPOSED [B,H,HD,S].
__global__ __launch_bounds__(256)
void gemm2(const unsigned short* __restrict__ A, const unsigned short* __restrict__ Bt,
           int M, int N, int K, float* __restrict__ Cf,
           unsigned short* __restrict__ qd, unsigned short* __restrict__ kd,
           unsigned short* __restrict__ vtd, int mode, int nblk) {
  __shared__ alignas(16) unsigned short lds[2][2][4096];  // [stage][A|B][128*32]
  const int tid = threadIdx.x;
  const int lane = tid & 63, l15 = lane & 15, lg = lane >> 4;
  const int wave = tid >> 6;
  const int wgid = blockIdx.x;
  const int xg = wgid & 7, tg = wgid >> 3;
  const int m0 = ((tg / nblk) * 8 + xg) * 128, n0 = (tg % nblk) * 128;
  const int wm = (wave >> 1) * 64, wn = (wave & 1) * 64;
  const int wbase = wave * 512;  // ushort units; gll16 dest is wave-uniform base + lane*16B
  const int grow = tid >> 2, gcol = (tid & 3) * 8;
  f32x4 acc[4][4] = {};
  const int nt = K / 32;

#define GSTAGE(sb, kk)                                                              \
  do {                                                                              \
    gll16(&A[(size_t)(m0 + grow) * K + (kk) + gcol], &lds[sb][0][wbase]);           \
    gll16(&A[(size_t)(m0 + 64 + grow) * K + (kk) + gcol], &lds[sb][0][2048 + wbase]);\
    gll16(&Bt[(size_t)(n0 + grow) * K + (kk) + gcol], &lds[sb][1][wbase]);          \
    gll16(&Bt[(size_t)(n0 + 64 + grow) * K + (kk) + gcol], &lds[sb][1][2048 + wbase]);\
  } while (0)

  GSTAGE(0, 0);
  asm volatile("s_waitcnt vmcnt(0)" ::: "memory");
  __syncthreads();
  for (int t = 0; t < nt; ++t) {
    const int cur = t & 1;
    if (t + 1 < nt) GSTAGE(cur ^ 1, (t + 1) * 32);
    bf16x8 af[4], bfr[4];
#pragma unroll
    for (int i = 0; i < 4; ++i) {
      af[i]  = *(const bf16x8*)&lds[cur][0][(wm + i * 16 + l15) * 32 + lg * 8];
      bfr[i] = *(const bf16x8*)&lds[cur][1][(wn + i * 16 + l15) * 32 + lg * 8];
    }
    __builtin_amdgcn_s_setprio(1);
#pragma unroll
    for (int i = 0; i < 4; ++i)
#pragma unroll
      for (int j = 0; j < 4; ++j)
        acc[i][j] = MFMA16(af[i], bfr[j], acc[i][j]);
    __builtin_amdgcn_s_setprio(0);
    asm volatile("s_waitcnt vmcnt(0)" ::: "memory");
    __syncthreads();
  }
#undef GSTAGE

  if (mode == 0) {
#pragma unroll
    for (int i = 0; i < 4; ++i)
#pragma unroll
      for (int j = 0; j < 4; ++j)
#pragma unroll
        for (int r = 0; r < 4; ++r)
          Cf[(size_t)(m0 + wm + i * 16 + lg * 4 + r) * N + (n0 + wn + j * 16 + l15)] = acc[i][j][r];
  } else {
    const int sel = n0 >> 9;  // block never crosses a 512 boundary
    const int nb = (n0 & 511) + wn;
    if (sel < 2) {
      unsigned short* dst = (sel == 0) ? qd : kd;
#pragma unroll
      for (int i = 0; i < 4; ++i)
#pragma unroll
        for (int j = 0; j < 4; ++j)
#pragma unroll
          for (int r = 0; r < 4; ++r) {
            const int m = m0 + wm + i * 16 + lg * 4 + r;
            const int nn = nb + j * 16 + l15;
            dst[(((size_t)(m >> 11) * 8 + (nn >> 6)) * 2048 + (m & 2047)) * 64 + (nn & 63)] =
                f2b(acc[i][j][r]);
          }
    } else {
      // V transposed: vtd[((b*8+h)*64 + hd)*2048 + s]
#pragma unroll
      for (int i = 0; i < 4; ++i)
#pragma unroll
        for (int j = 0; j < 4; ++j)
#pragma unroll
          for (int r = 0; r < 4; ++r) {
            const int m = m0 + wm + i * 16 + lg * 4 + r;
            const int nn = nb + j * 16 + l15;
            vtd[(((size_t)(m >> 11) * 8 + (nn >> 6)) * 64 + (nn & 63)) * 2048 + (m & 2047)] =
                f2b(acc[i][j][r]);
          }
    }
  }
}

// ------------- RoPE, head pair (h, h+4) per thread: each q/k element read ONCE -------------
__global__ void rope_pair_kernel(const unsigned short* __restrict__ qpre, const unsigned short* __restrict__ kpre,
                                 const float* __restrict__ cose, const float* __restrict__ sine,
                                 unsigned short* __restrict__ qb, unsigned short* __restrict__ kb) {
  const int idx = blockIdx.x * 256 + threadIdx.x;  // 0 .. B*4*S*8-1
  const int hd0 = (idx & 7) * 8;
  const int rr = idx >> 3;           // (b*4 + h)*2048 + s, h in 0..3
  const int b = rr >> 13, h = (rr >> 11) & 3, s = rr & 2047;
  const size_t lo = ((size_t)(b * 8 + h) * 2048 + s) * 64 + hd0;
  const size_t hi = lo + (size_t)4 * 2048 * 64;
  const int d0 = h * 64 + hd0;       // < 256
  short8 qlo = *(const short8*)&qpre[lo];
  short8 qhi = *(const short8*)&qpre[hi];
  short8 klo = *(const short8*)&kpre[lo];
  short8 khi = *(const short8*)&kpre[hi];
  float4 c0 = *(const float4*)&cose[(size_t)s * 512 + d0];
  float4 c1 = *(const float4*)&cose[(size_t)s * 512 + d0 + 4];
  float4 s0 = *(const float4*)&sine[(size_t)s * 512 + d0];
  float4 s1 = *(const float4*)&sine[(size_t)s * 512 + d0 + 4];
  float cc[8] = {c0.x, c0.y, c0.z, c0.w, c1.x, c1.y, c1.z, c1.w};
  float ss[8] = {s0.x, s0.y, s0.z, s0.w, s1.x, s1.y, s1.z, s1.w};
  short8 qolo, qohi, kolo, kohi;
#pragma unroll
  for (int j = 0; j < 8; ++j) {
    float ql = b2f((unsigned short)qlo[j]), qh = b2f((unsigned short)qhi[j]);
    float kl = b2f((unsigned short)klo[j]), kh = b2f((unsigned short)khi[j]);
    qolo[j] = (short)f2b((ql * cc[j] - qh * ss[j]) * QSCALE);
    qohi[j] = (short)f2b((qh * cc[j] + ql * ss[j]) * QSCALE);
    kolo[j] = (short)f2b(kl * cc[j] - kh * ss[j]);
    kohi[j] = (short)f2b(kh * cc[j] + kl * ss[j]);
  }
  *(short8*)&qb[lo] = qolo;
  *(short8*)&qb[hi] = qohi;
  *(short8*)&kb[lo] = kolo;
  *(short8*)&kb[hi] = kohi;
}

// ------------- flash attention, 32x32x16 MFMA, split-K, 2-buf KV staging -------------
// 4 waves x 32 q-rows = 128 q/block; grid 1024 = 8 xcd x 4 bh x 2 khalf x 16 qchunk.
// LDS traffic per score HALVED vs 16x16 (each wave's K/V tile reads now cover 32 q-rows).
// K rows staged permuted: pi(rho) = 32(rho>>5) | 16((rho>>4)&1) | 8((rho>>2)&1) | 4((rho>>3)&1) | (rho&3)
// so each lane's 32 QK score slots are exactly its PV A-fragments (P never leaves registers).
// Scores in log2 domain; raw v_exp_f32 (FTZ: mask bias -300 -> exact 0); no running max.
__global__ __launch_bounds__(256, 4)
void flash_kernel(const unsigned short* __restrict__ qb, const unsigned short* __restrict__ kb,
                  const unsigned short* __restrict__ vtb, const unsigned long long* __restrict__ mbits,
                  float* __restrict__ op0, float* __restrict__ op1,
                  float* __restrict__ ls0, float* __restrict__ ls1) {
  __shared__ alignas(16) unsigned short kv[2][2][4096];   // [stage][K|V][64x64 bf16], src-swizzled
  __shared__ alignas(16) f32x4 btab[16];                  // nibble -> bias4 (0 or -300 per bit)
  const int tid = threadIdx.x;
  const int wave = tid >> 6, lane = tid & 63;
  const int l31 = lane & 31, lh = lane >> 5;
  const int swz7 = l31 & 7;
  const int wgid = blockIdx.x;
  const int slot = wgid >> 3;
  const int bh = (wgid & 7) * 4 + (slot & 3);
  const int rest = slot >> 2;            // 0..31
  const int kh = rest & 1;
  const int q0 = (rest >> 1) * 128 + wave * 32;
  const int b = bh >> 3, h = bh & 7;
  const int kbase = kh * 1024;
  const unsigned short* Q = qb + ((size_t)bh * S + q0) * HD;
  const unsigned short* Kp = kb + (size_t)bh * S * HD;
  const unsigned short* Vt = vtb + (size_t)bh * HD * S;
  const unsigned long long* Mrow = mbits + ((size_t)b * S + q0 + l31) * (S / 64) + kh * 16;
  float* opart = kh ? op1 : op0;
  float* lsum = kh ? ls1 : ls0;

  // staging: 256 threads x 16B x 2 calls = one 64x64 tile; source pre-swizzled (rule #21)
  const int srow = tid >> 3;             // rows 0..31 (call0), +32 (call1)
  const int ch = tid & 7;
  const int scol = (ch ^ (srow & 7)) * 8;
  // K row permutation pi: low-5-bit part (same for both calls since (srow+32)&31 == srow)
  const int pif = 16 * ((srow >> 4) & 1) + 8 * ((srow >> 2) & 1) + 4 * ((srow >> 3) & 1) + (srow & 3);
  const int wbase = wave * 512;  // ushort units (wave-uniform); call1 at +2048

  if (tid < 16) {
    f32x4 e;
    e[0] = (tid & 1) ? 0.f : -300.f;
    e[1] = (tid & 2) ? 0.f : -300.f;
    e[2] = (tid & 4) ? 0.f : -300.f;
    e[3] = (tid & 8) ? 0.f : -300.f;
    btab[tid] = e;
  }

  // Q B-frags: lane holds Q[q=l31][hd = 16*wp + 8*lh + j]
  bf16x8 qf[4];
#pragma unroll
  for (int wp = 0; wp < 4; ++wp)
    qf[wp] = *(const bf16x8*)&Q[l31 * HD + wp * 16 + 8 * lh];
  f32x16 o0 = {}, o1 = {};
  float lpart = 0.f;
  const int mb = lh * 8;

#define FSTAGE(sb, kn)                                                               \
  do {                                                                               \
    gll16(&Kp[(size_t)((kn) + pif) * HD + scol], &kv[sb][0][wbase]);                 \
    gll16(&Kp[(size_t)((kn) + 32 + pif) * HD + scol], &kv[sb][0][2048 + wbase]);     \
    gll16(&Vt[(size_t)srow * S + (kn) + scol], &kv[sb][1][wbase]);                   \
    gll16(&Vt[(size_t)(srow + 32) * S + (kn) + scol], &kv[sb][1][2048 + wbase]);     \
  } while (0)

  unsigned long long wA = Mrow[0];
  FSTAGE(0, kbase);
  asm volatile("s_waitcnt vmcnt(0) lgkmcnt(0)" ::: "memory");
  __syncthreads();

  for (int t = 0; t < 16; ++t) {
    const int cur = t & 1;
    unsigned long long wB = 0;
    if (t + 1 < 16) {
      FSTAGE(cur ^ 1, kbase + (t + 1) * KBLK);
      wB = Mrow[t + 1];
    }
    const char* kbp = (const char*)&kv[cur][0][0];
    const char* vbp = (const char*)&kv[cur][1][0];

    // ---- QK^T: sc[c] = mfma32(K-chunk-c, Q); lane owns q=l31, 16 k-slots per chunk ----
    f32x16 sc0 = {}, sc1 = {};
    __builtin_amdgcn_s_setprio(1);
#pragma unroll
    for (int wp = 0; wp < 4; ++wp) {
      const int cs = ((2 * wp + lh) ^ swz7) * 16;
      bf16x8 kf0 = *(const bf16x8*)(kbp + l31 * 128 + cs);
      bf16x8 kf1 = *(const bf16x8*)(kbp + (32 + l31) * 128 + cs);
      sc0 = MFMA32(kf0, qf[wp], sc0);
      sc1 = MFMA32(kf1, qf[wp], sc1);
    }
    __builtin_amdgcn_s_setprio(0);

    // ---- p = v_exp(s + bias); mask bit for (c,r) = 32c + 8lh + 16(r>>3) + 4((r>>2)&1) + (r&3) ----
    const f32x4 b00 = btab[(unsigned)(wA >> (mb + 0)) & 15u];
    const f32x4 b01 = btab[(unsigned)(wA >> (mb + 4)) & 15u];
    const f32x4 b02 = btab[(unsigned)(wA >> (mb + 16)) & 15u];
    const f32x4 b03 = btab[(unsigned)(wA >> (mb + 20)) & 15u];
    const f32x4 b10 = btab[(unsigned)(wA >> (mb + 32)) & 15u];
    const f32x4 b11 = btab[(unsigned)(wA >> (mb + 36)) & 15u];
    const f32x4 b12 = btab[(unsigned)(wA >> (mb + 48)) & 15u];
    const f32x4 b13 = btab[(unsigned)(wA >> (mb + 52)) & 15u];
    f32x16 pv0, pv1;
#pragma unroll
    for (int r = 0; r < 16; ++r) {
      const int bi = 2 * (r >> 3) + ((r >> 2) & 1);
      const float e0 = (bi == 0) ? b00[r & 3] : (bi == 1) ? b01[r & 3] : (bi == 2) ? b02[r & 3] : b03[r & 3];
      const float e1 = (bi == 0) ? b10[r & 3] : (bi == 1) ? b11[r & 3] : (bi == 2) ? b12[r & 3] : b13[r & 3];
      pv0[r] = __builtin_amdgcn_exp2f(sc0[r] + e0);
      pv1[r] = __builtin_amdgcn_exp2f(sc1[r] + e1);
    }
    float rs = 0.f;
#pragma unroll
    for (int r = 0; r < 16; ++r) rs += pv0[r] + pv1[r];
    lpart += rs;

    // ---- P -> bf16 A-frags in-register: pf[w][j] = pv[w>>1][(j&3) + 4*(j>>2) + 8*(w&1)] ----
    bf16x8 pf[4];
#pragma unroll
    for (int j = 0; j < 8; ++j) {
      const int rr = (j & 3) + 4 * (j >> 2);
      pf[0][j] = (__bf16)pv0[rr];
      pf[1][j] = (__bf16)pv0[rr + 8];
      pf[2][j] = (__bf16)pv1[rr];
      pf[3][j] = (__bf16)pv1[rr + 8];
    }

    // ---- PV: o[dh] += mfma32(pf[w], V[k-window w][d-half dh]) ----
    __builtin_amdgcn_s_setprio(1);
#pragma unroll
    for (int w = 0; w < 4; ++w) {
      const int cs = ((2 * w + lh) ^ swz7) * 16;
      bf16x8 vf0 = *(const bf16x8*)(vbp + l31 * 128 + cs);
      bf16x8 vf1 = *(const bf16x8*)(vbp + (32 + l31) * 128 + cs);
      o0 = MFMA32(pf[w], vf0, o0);
      o1 = MFMA32(pf[w], vf1, o1);
    }
    __builtin_amdgcn_s_setprio(0);

    asm volatile("s_waitcnt vmcnt(0)" ::: "memory");  // next tile landed
    __syncthreads();
    wA = wB;
  }
#undef FSTAGE

  // ---- row-sum: lane halves hold complementary k; one xor ----
  lpart += __shfl_xor(lpart, 32);
  if (lh == 0) lsum[(size_t)bh * S + q0 + l31] = lpart;
  // ---- store un-normalized partials: q-row = (r&3)+8*(r>>2)+4*lh, d = 32*dh + l31 ----
#pragma unroll
  for (int r = 0; r < 16; ++r) {
    const size_t row = (size_t)(b * S + q0 + (r & 3) + 8 * (r >> 2) + 4 * lh) * D + h * HD;
    opart[row + l31] = o0[r];
    opart[row + 32 + l31] = o1[r];
  }
}

// ------------- fused out GEMM: A = (op0+op1)*inv[row][head] cast to bf16 in staging -------------
// XCD-grouped linear grid (m-panel per XCD): x=wgid&7, t=wgid>>3, n=t&3, m=(t>>2)*8+x.
__global__ __launch_bounds__(256)
void gemm_fused(const float* __restrict__ op0, const float* __restrict__ op1,
                const float* __restrict__ ls0, const float* __restrict__ ls1,
                const unsigned short* __restrict__ Bt, float* __restrict__ C) {
  __shared__ alignas(16) unsigned short ldsA[2][2048];  // [stage][64*32]
  __shared__ alignas(16) unsigned short ldsB[2][4096];  // [stage][128*32]
  __shared__ float invt[512];                           // [row64][head8]
  const int tid = threadIdx.x;
  const int lane = tid & 63, l15 = lane & 15, lg = lane >> 4;
  const int wave = tid >> 6;
  const int wgid = blockIdx.x;
  const int xg = wgid & 7, tg = wgid >> 3;
  const int m0 = ((tg >> 2) * 8 + xg) * 64, n0 = (tg & 3) * 128;
  const int wm = (wave >> 1) * 32, wn = (wave & 1) * 64;
  const int wbase = wave * 512;
  const int grow = tid >> 2, gcol = (tid & 3) * 8;
  const size_t abase = (size_t)(m0 + (tid >> 2)) * 512 + (tid & 3) * 8;
  f32x4 acc[2][4] = {};

  for (int e = tid; e < 512; e += 256) {
    const int row = e >> 3, hh = e & 7;
    const int m = m0 + row;
    const size_t li = ((size_t)((m >> 11) * 8 + hh)) * 2048 + (m & 2047);
    const float l = ls0[li] + ls1[li];
    invt[e] = (l > 0.f) ? 1.f / l : 0.f;
  }

#define BSTAGE(sb, kk)                                                               \
  do {                                                                               \
    gll16(&Bt[(size_t)(n0 + grow) * 512 + (kk) + gcol], &ldsB[sb][wbase]);           \
    gll16(&Bt[(size_t)(n0 + 64 + grow) * 512 + (kk) + gcol], &ldsB[sb][2048 + wbase]);\
  } while (0)

  float4 a0, a1, p0, p1;
#define ALOAD(kk)                                          \
  do {                                                     \
    a0 = *(const float4*)&op0[abase + (kk)];               \
    a1 = *(const float4*)&op0[abase + (kk) + 4];           \
    p0 = *(const float4*)&op1[abase + (kk)];               \
    p1 = *(const float4*)&op1[abase + (kk) + 4];           \
  } while (0)

#define AWRITE(sb, kk)                                                       \
  do {                                                                       \
    const float inv = invt[((tid >> 2) << 3) | ((kk) >> 6)];                 \
    short8 pk;                                                               \
    pk[0] = (short)f2b((a0.x + p0.x) * inv);                                 \
    pk[1] = (short)f2b((a0.y + p0.y) * inv);                                 \
    pk[2] = (short)f2b((a0.z + p0.z) * inv);                                 \
    pk[3] = (short)f2b((a0.w + p0.w) * inv);                                 \
    pk[4] = (short)f2b((a1.x + p1.x) * inv);                                 \
    pk[5] = (short)f2b((a1.y + p1.y) * inv);                                 \
    pk[6] = (short)f2b((a1.z + p1.z) * inv);                                 \
    pk[7] = (short)f2b((a1.w + p1.w) * inv);                                 \
    *(short8*)&ldsA[sb][(tid >> 2) * 32 + (tid & 3) * 8] = pk;               \
  } while (0)

  ALOAD(0);
  BSTAGE(0, 0);
  __syncthreads();          // invt visible; drains A loads + B gll16
  AWRITE(0, 0);
  __syncthreads();          // A(0) visible

  for (int t = 0; t < 16; ++t) {
    const int cur = t & 1;
    const bool have = (t + 1 < 16);
    if (have) { ALOAD((t + 1) * 32); BSTAGE(cur ^ 1, (t + 1) * 32); }
    bf16x8 af[2], bfr[4];
#pragma unroll
    for (int i = 0; i < 2; ++i)
      af[i] = *(const bf16x8*)&ldsA[cur][(wm + i * 16 + l15) * 32 + lg * 8];
#pragma unroll
    for (int j = 0; j < 4; ++j)
      bfr[j] = *(const bf16x8*)&ldsB[cur][(wn + j * 16 + l15) * 32 + lg * 8];
    __builtin_amdgcn_s_setprio(1);
#pragma unroll
    for (int i = 0; i < 2; ++i)
#pragma unroll
      for (int j = 0; j < 4; ++j)
        acc[i][j] = MFMA16(af[i], bfr[j], acc[i][j]);
    __builtin_amdgcn_s_setprio(0);
    asm volatile("s_waitcnt vmcnt(0)" ::: "memory");
    __syncthreads();
    if (have) AWRITE(cur ^ 1, (t + 1) * 32);
    __syncthreads();
  }
#undef BSTAGE
#undef ALOAD
#undef AWRITE

#pragma unroll
  for (int i = 0; i < 2; ++i)
#pragma unroll
    for (int j = 0; j < 4; ++j)
#pragma unroll
      for (int r = 0; r < 4; ++r)
        C[(size_t)(m0 + wm + i * 16 + lg * 4 + r) * 512 + (n0 + wn + j * 16 + l15)] = acc[i][j][r];
}

extern "C" void kernel_launch(void* const* d_in, const int* in_sizes, int n_in,
                              void* d_out, int out_size, void* d_ws, size_t ws_size,
                              hipStream_t stream) {
  const float* x = (const float*)d_in[0];
  const float* cose = (const float*)d_in[1];
  const float* sine = (const float*)d_in[2];
  const int* mask = (const int*)d_in[3];
  const float* wq = (const float*)d_in[4];
  const float* wk = (const float*)d_in[5];
  const float* wv = (const float*)d_in[6];
  const float* wo = (const float*)d_in[7];
  float* out = (float*)d_out;
  char* ws = (char*)d_ws;

  // workspace layout (bytes)
  unsigned short* xb    = (unsigned short*)(ws);                 //  8,388,608  x bf16 [8192][512]
  unsigned short* wqkvT = (unsigned short*)(ws + 8388608);       //  1,572,864  [1536][512]
  unsigned short* woT   = (unsigned short*)(ws + 9961472);       //    524,288  [512][512]
  unsigned short* qpre  = (unsigned short*)(ws + 10485760);      //  8,388,608  [B,H,S,HD] pre-rope
  unsigned short* kpre  = (unsigned short*)(ws + 18874368);      //  8,388,608
  unsigned short* qbh   = (unsigned short*)(ws + 35651584);      //  8,388,608  post-rope
  unsigned short* kbh   = (unsigned short*)(ws + 44040192);      //  8,388,608
  unsigned short* vtb   = (unsigned short*)(ws + 52428800);      //  8,388,608  [B,H,HD,S]
  unsigned long long* mbits = (unsigned long long*)(ws + 60817408);  // 2,097,152
  float* op0 = (float*)(ws + 10485760);   // 16,777,216  (over qpre+kpre; dead when flash runs)
  float* op1 = (float*)(ws + 62914560);   // 16,777,216
  float* ls0 = (float*)(ws + 79691776);   //    262,144
  float* ls1 = (float*)(ws + 79953920);   //    262,144  (ends 80,216,064)

  maskbits_kernel<<<65536, 256, 0, stream>>>(mask, mbits);
  cast_x_kernel<<<4096, 256, 0, stream>>>(x, xb);
  wtrans4_kernel<<<dim3(8, 8, 4), 256, 0, stream>>>(wq, wk, wv, wo, wqkvT, woT);
  gemm2<<<768, 256, 0, stream>>>(xb, wqkvT, 8192, 1536, 512, nullptr, qpre, kpre, vtb, 1, 12);
  rope_pair_kernel<<<1024, 256, 0, stream>>>(qpre, kpre, cose, sine, qbh, kbh);
  flash_kernel<<<1024, 256, 0, stream>>>(qbh, kbh, vtb, mbits, op0, op1, ls0, ls1);
  gemm_fused<<<512, 256, 0, stream>>>(op0, op1, ls0, ls1, woT, out);
}

// Round 12
// 130.916 us; speedup vs baseline: 1.3359x; 1.3359x over previous
//
#include <hip/hip_runtime.h>
#include <hip/hip_bf16.h>

typedef __bf16 bf16x8 __attribute__((ext_vector_type(8)));
typedef float f32x4 __attribute__((ext_vector_type(4)));
typedef float f32x16 __attribute__((ext_vector_type(16)));
typedef short short8 __attribute__((ext_vector_type(8)));

#define MFMA16(a, b, c) __builtin_amdgcn_mfma_f32_16x16x32_bf16((a), (b), (c), 0, 0, 0)
#define MFMA32(a, b, c) __builtin_amdgcn_mfma_f32_32x32x16_bf16((a), (b), (c), 0, 0, 0)

static constexpr int S = 2048;
static constexpr int D = 512;
static constexpr int HD = 64;
static constexpr int KBLK = 64;
// q scale: 1/sqrt(HD) * log2(e), so softmax can use exp2
#define QSCALE 0.18033688011112042f

typedef __attribute__((address_space(1))) const unsigned int gu32;
typedef __attribute__((address_space(3))) unsigned int lu32;

__device__ __forceinline__ void gll16(const void* g, void* l) {
  __builtin_amdgcn_global_load_lds((gu32*)g, (lu32*)l, 16, 0, 0);
}

__device__ __forceinline__ unsigned short f2b(float f) {
  return __builtin_bit_cast(unsigned short, __float2bfloat16(f));
}
__device__ __forceinline__ float b2f(unsigned short u) {
  return __builtin_bit_cast(float, (unsigned)u << 16);
}

// ---------------- mask (int32 0/1) -> bitmask [B*S][S/64] u64, grid-stride ----------------
__global__ void maskbits_kernel(const int* __restrict__ m, unsigned long long* __restrict__ bits) {
  const int stride = 2048 * 256;
  const int lane0 = (threadIdx.x & 63) == 0;
  for (int gid = blockIdx.x * 256 + threadIdx.x; gid < 4 * 2048 * 2048; gid += stride) {
    unsigned long long w = __ballot(m[gid] != 0);
    if (lane0) bits[gid >> 6] = w;
  }
}

// ---------------- cast x (f32 -> bf16), 4 elems/thread ----------------
__global__ void cast_x_kernel(const float* __restrict__ x, unsigned short* __restrict__ xb) {
  int idx = blockIdx.x * 256 + threadIdx.x;
  float4 v = ((const float4*)x)[idx];
  ushort4 o;
  o.x = f2b(v.x); o.y = f2b(v.y); o.z = f2b(v.z); o.w = f2b(v.w);
  ((ushort4*)xb)[idx] = o;
}

// ------------- tiled transpose+cast of the 4 weight matrices -------------
__global__ void wtrans4_kernel(const float* __restrict__ wq, const float* __restrict__ wk,
                               const float* __restrict__ wv, const float* __restrict__ wo,
                               unsigned short* __restrict__ wqkvT, unsigned short* __restrict__ woT) {
  __shared__ float t[64][65];
  const int z = blockIdx.z;
  const float* w = (z == 0) ? wq : (z == 1) ? wk : (z == 2) ? wv : wo;
  unsigned short* dst = (z < 3) ? wqkvT + (size_t)z * 512 * 512 : woT;
  const int i0 = blockIdx.x * 64, o0 = blockIdx.y * 64;
  for (int it = 0; it < 16; ++it) {
    int idx = it * 256 + threadIdx.x;
    int ii = idx >> 6, oo = idx & 63;
    t[oo][ii] = w[(size_t)(i0 + ii) * 512 + o0 + oo];
  }
  __syncthreads();
  for (int it = 0; it < 16; ++it) {
    int idx = it * 256 + threadIdx.x;
    int oo = idx >> 6, ii = idx & 63;
    dst[(size_t)(o0 + oo) * 512 + i0 + ii] = f2b(t[oo][ii]);
  }
}

// ------------- GEMM: C = A[M][K] * Bt[N][K]^T, gll16-staged dbuf, 128x128 tile BK=32 -------------
// mode 0: f32 C row-major. mode 1: bf16 per-head scatter: q/k pre-rope [B,H,S,HD]; V TRANSPOSED [B,H,HD,S].
__global__ __launch_bounds__(256)
void gemm2(const unsigned short* __restrict__ A, const unsigned short* __restrict__ Bt,
           int M, int N, int K, float* __restrict__ Cf,
           unsigned short* __restrict__ qd, unsigned short* __restrict__ kd,
           unsigned short* __restrict__ vtd, int mode) {
  __shared__ alignas(16) unsigned short lds[2][2][4096];  // [stage][A|B][128*32]
  const int tid = threadIdx.x;
  const int lane = tid & 63, l15 = lane & 15, lg = lane >> 4;
  const int wave = tid >> 6;
  const int m0 = blockIdx.x * 128, n0 = blockIdx.y * 128;
  const int wm = (wave >> 1) * 64, wn = (wave & 1) * 64;
  const int wbase = wave * 512;  // ushort units; gll16 dest is wave-uniform base + lane*16B
  const int grow = tid >> 2, gcol = (tid & 3) * 8;
  f32x4 acc[4][4] = {};
  const int nt = K / 32;

#define GSTAGE(sb, kk)                                                              \
  do {                                                                              \
    gll16(&A[(size_t)(m0 + grow) * K + (kk) + gcol], &lds[sb][0][wbase]);           \
    gll16(&A[(size_t)(m0 + 64 + grow) * K + (kk) + gcol], &lds[sb][0][2048 + wbase]);\
    gll16(&Bt[(size_t)(n0 + grow) * K + (kk) + gcol], &lds[sb][1][wbase]);          \
    gll16(&Bt[(size_t)(n0 + 64 + grow) * K + (kk) + gcol], &lds[sb][1][2048 + wbase]);\
  } while (0)

  GSTAGE(0, 0);
  asm volatile("s_waitcnt vmcnt(0)" ::: "memory");
  __syncthreads();
  for (int t = 0; t < nt; ++t) {
    const int cur = t & 1;
    if (t + 1 < nt) GSTAGE(cur ^ 1, (t + 1) * 32);
    bf16x8 af[4], bfr[4];
#pragma unroll
    for (int i = 0; i < 4; ++i) {
      af[i]  = *(const bf16x8*)&lds[cur][0][(wm + i * 16 + l15) * 32 + lg * 8];
      bfr[i] = *(const bf16x8*)&lds[cur][1][(wn + i * 16 + l15) * 32 + lg * 8];
    }
    __builtin_amdgcn_s_setprio(1);
#pragma unroll
    for (int i = 0; i < 4; ++i)
#pragma unroll
      for (int j = 0; j < 4; ++j)
        acc[i][j] = MFMA16(af[i], bfr[j], acc[i][j]);
    __builtin_amdgcn_s_setprio(0);
    asm volatile("s_waitcnt vmcnt(0)" ::: "memory");
    __syncthreads();
  }
#undef GSTAGE

  if (mode == 0) {
#pragma unroll
    for (int i = 0; i < 4; ++i)
#pragma unroll
      for (int j = 0; j < 4; ++j)
#pragma unroll
        for (int r = 0; r < 4; ++r)
          Cf[(size_t)(m0 + wm + i * 16 + lg * 4 + r) * N + (n0 + wn + j * 16 + l15)] = acc[i][j][r];
  } else {
    const int sel = n0 >> 9;  // block never crosses a 512 boundary
    const int nb = (n0 & 511) + wn;
    if (sel < 2) {
      unsigned short* dst = (sel == 0) ? qd : kd;
#pragma unroll
      for (int i = 0; i < 4; ++i)
#pragma unroll
        for (int j = 0; j < 4; ++j)
#pragma unroll
          for (int r = 0; r < 4; ++r) {
            const int m = m0 + wm + i * 16 + lg * 4 + r;
            const int nn = nb + j * 16 + l15;
            dst[(((size_t)(m >> 11) * 8 + (nn >> 6)) * 2048 + (m & 2047)) * 64 + (nn & 63)] =
                f2b(acc[i][j][r]);
          }
    } else {
      // V transposed: vtd[((b*8+h)*64 + hd)*2048 + s]
#pragma unroll
      for (int i = 0; i < 4; ++i)
#pragma unroll
        for (int j = 0; j < 4; ++j)
#pragma unroll
          for (int r = 0; r < 4; ++r) {
            const int m = m0 + wm + i * 16 + lg * 4 + r;
            const int nn = nb + j * 16 + l15;
            vtd[(((size_t)(m >> 11) * 8 + (nn >> 6)) * 64 + (nn & 63)) * 2048 + (m & 2047)] =
                f2b(acc[i][j][r]);
          }
    }
  }
}

// ------------- RoPE, head pair (h, h+4) per thread: each q/k element read ONCE -------------
__global__ void rope_pair_kernel(const unsigned short* __restrict__ qpre, const unsigned short* __restrict__ kpre,
                                 const float* __restrict__ cose, const float* __restrict__ sine,
                                 unsigned short* __restrict__ qb, unsigned short* __restrict__ kb) {
  const int idx = blockIdx.x * 256 + threadIdx.x;  // 0 .. B*4*S*8-1
  const int hd0 = (idx & 7) * 8;
  const int rr = idx >> 3;           // (b*4 + h)*2048 + s, h in 0..3
  const int b = rr >> 13, h = (rr >> 11) & 3, s = rr & 2047;
  const size_t lo = ((size_t)(b * 8 + h) * 2048 + s) * 64 + hd0;
  const size_t hi = lo + (size_t)4 * 2048 * 64;
  const int d0 = h * 64 + hd0;       // < 256
  short8 qlo = *(const short8*)&qpre[lo];
  short8 qhi = *(const short8*)&qpre[hi];
  short8 klo = *(const short8*)&kpre[lo];
  short8 khi = *(const short8*)&kpre[hi];
  float4 c0 = *(const float4*)&cose[(size_t)s * 512 + d0];
  float4 c1 = *(const float4*)&cose[(size_t)s * 512 + d0 + 4];
  float4 s0 = *(const float4*)&sine[(size_t)s * 512 + d0];
  float4 s1 = *(const float4*)&sine[(size_t)s * 512 + d0 + 4];
  float cc[8] = {c0.x, c0.y, c0.z, c0.w, c1.x, c1.y, c1.z, c1.w};
  float ss[8] = {s0.x, s0.y, s0.z, s0.w, s1.x, s1.y, s1.z, s1.w};
  short8 qolo, qohi, kolo, kohi;
#pragma unroll
  for (int j = 0; j < 8; ++j) {
    float ql = b2f((unsigned short)qlo[j]), qh = b2f((unsigned short)qhi[j]);
    float kl = b2f((unsigned short)klo[j]), kh = b2f((unsigned short)khi[j]);
    qolo[j] = (short)f2b((ql * cc[j] - qh * ss[j]) * QSCALE);
    qohi[j] = (short)f2b((qh * cc[j] + ql * ss[j]) * QSCALE);
    kolo[j] = (short)f2b(kl * cc[j] - kh * ss[j]);
    kohi[j] = (short)f2b(kh * cc[j] + kl * ss[j]);
  }
  *(short8*)&qb[lo] = qolo;
  *(short8*)&qb[hi] = qohi;
  *(short8*)&kb[lo] = kolo;
  *(short8*)&kb[hi] = kohi;
}

// ------------- flash16 (proven r9 structure): kh=1 half. 512 thr, 8 waves x 16 q-rows -------------
// grid 512 = 8 xcd x 4 bh x 16 qchunk. Un-normalized f32 partials + row-sums to op1/ls1.
__global__ __launch_bounds__(512)
void flash16_kernel(const unsigned short* __restrict__ qb, const unsigned short* __restrict__ kb,
                    const unsigned short* __restrict__ vtb, const unsigned long long* __restrict__ mbits,
                    float* __restrict__ opart, float* __restrict__ lsum) {
  __shared__ alignas(16) unsigned short kv[2][2][4096];   // [stage][K|V][64x64 bf16], src-swizzled
  __shared__ alignas(16) f32x4 btab[16];
  const int tid = threadIdx.x;
  const int wave = tid >> 6, lane = tid & 63;
  const int l15 = lane & 15, lg = lane >> 4;
  const int swz = (l15 & 7) << 4;
  const int wgid = blockIdx.x;
  const int slot = wgid >> 3;
  const int bh = (wgid & 7) * 4 + (slot & 3);
  const int rest = slot >> 2;            // 0..15 = qchunk
  const int q0 = rest * 128 + wave * 16;
  const int b = bh >> 3, h = bh & 7;
  const int kbase = 1024;                // kh = 1
  const unsigned short* Q = qb + ((size_t)bh * S + q0) * HD;
  const unsigned short* Kp = kb + (size_t)bh * S * HD;
  const unsigned short* Vt = vtb + (size_t)bh * HD * S;
  const unsigned long long* Mrow = mbits + ((size_t)b * S + q0 + l15) * (S / 64) + 16;

  const int srow = tid >> 3;
  const int scol = ((tid & 7) ^ (srow & 7)) * 8;
  const int ksrow = ((srow & 15) >> 2) * 8 + ((srow >> 4) & 1) * 4 + (srow & 3) + (srow >> 5) * 32;
  const int wbase = wave * 512;

  if (tid < 16) {
    f32x4 e;
    e[0] = (tid & 1) ? 0.f : -300.f;
    e[1] = (tid & 2) ? 0.f : -300.f;
    e[2] = (tid & 4) ? 0.f : -300.f;
    e[3] = (tid & 8) ? 0.f : -300.f;
    btab[tid] = e;
  }

  bf16x8 qf0 = *(const bf16x8*)&Q[l15 * HD + lg * 8];
  bf16x8 qf1 = *(const bf16x8*)&Q[l15 * HD + 32 + lg * 8];
  f32x4 o[4] = {};
  float lpart = 0.f;
  const int lgs8 = lg * 8;

  unsigned long long wA = Mrow[0];
  gll16(&Kp[(size_t)(kbase + ksrow) * HD + scol], &kv[0][0][wbase]);
  gll16(&Vt[(size_t)srow * S + kbase + scol], &kv[0][1][wbase]);
  asm volatile("s_waitcnt vmcnt(0) lgkmcnt(0)" ::: "memory");
  __syncthreads();

  for (int t = 0; t < 16; ++t) {
    const int cur = t & 1;
    unsigned long long wB = 0;
    if (t + 1 < 16) {
      const int kn = kbase + (t + 1) * KBLK;
      gll16(&Kp[(size_t)(kn + ksrow) * HD + scol], &kv[cur ^ 1][0][wbase]);
      gll16(&Vt[(size_t)srow * S + kn + scol], &kv[cur ^ 1][1][wbase]);
      wB = Mrow[t + 1];
    }
    const char* kbp = (const char*)&kv[cur][0][0];
    const char* vbp = (const char*)&kv[cur][1][0];

    f32x4 sc[4] = {};
    __builtin_amdgcn_s_setprio(1);
#pragma unroll
    for (int n = 0; n < 4; ++n) {
      const int cb = (n * 16 + l15) * 128 + ((lg * 16) ^ swz);
      bf16x8 kf0 = *(const bf16x8*)(kbp + cb);
      bf16x8 kf1 = *(const bf16x8*)(kbp + (cb ^ 64));
      sc[n] = MFMA16(kf0, qf0, sc[n]);  // swapped: lane owns q=l15, k=pi(n*16+lg*4+r)
      sc[n] = MFMA16(kf1, qf1, sc[n]);
    }
    __builtin_amdgcn_s_setprio(0);

    f32x4 pv[4];
    {
      const f32x4 b0 = btab[(unsigned)(wA >> (lgs8 + 0)) & 15u];
      const f32x4 b1 = btab[(unsigned)(wA >> (lgs8 + 4)) & 15u];
      const f32x4 b2 = btab[(unsigned)(wA >> (lgs8 + 32)) & 15u];
      const f32x4 b3 = btab[(unsigned)(wA >> (lgs8 + 36)) & 15u];
#pragma unroll
      for (int r = 0; r < 4; ++r) {
        pv[0][r] = __builtin_amdgcn_exp2f(sc[0][r] + b0[r]);
        pv[1][r] = __builtin_amdgcn_exp2f(sc[1][r] + b1[r]);
        pv[2][r] = __builtin_amdgcn_exp2f(sc[2][r] + b2[r]);
        pv[3][r] = __builtin_amdgcn_exp2f(sc[3][r] + b3[r]);
      }
    }
    f32x4 s4 = (pv[0] + pv[1]) + (pv[2] + pv[3]);
    lpart += (s4[0] + s4[1]) + (s4[2] + s4[3]);

    bf16x8 pf0, pf1;
#pragma unroll
    for (int j = 0; j < 4; ++j) {
      pf0[j]     = (__bf16)pv[0][j];
      pf0[j + 4] = (__bf16)pv[1][j];
      pf1[j]     = (__bf16)pv[2][j];
      pf1[j + 4] = (__bf16)pv[3][j];
    }

    __builtin_amdgcn_s_setprio(1);
#pragma unroll
    for (int n = 0; n < 4; ++n) {
      const int cb = (n * 16 + l15) * 128 + ((lg * 16) ^ swz);
      bf16x8 vf0 = *(const bf16x8*)(vbp + cb);
      bf16x8 vf1 = *(const bf16x8*)(vbp + (cb ^ 64));
      o[n] = MFMA16(pf0, vf0, o[n]);
      o[n] = MFMA16(pf1, vf1, o[n]);
    }
    __builtin_amdgcn_s_setprio(0);

    asm volatile("s_waitcnt vmcnt(0)" ::: "memory");
    __syncthreads();
    wA = wB;
  }

  lpart += __shfl_xor(lpart, 16);
  lpart += __shfl_xor(lpart, 32);
  if (lg == 0) lsum[(size_t)bh * S + q0 + l15] = lpart;
#pragma unroll
  for (int r = 0; r < 4; ++r)
#pragma unroll
    for (int n = 0; n < 4; ++n)
      opart[((size_t)(b * S + q0 + lg * 4 + r)) * D + h * HD + n * 16 + l15] = o[n][r];
}

// ------------- flash32 (fixed retry): kh=0 half. 256 thr, 4 waves x 32 q-rows -------------
// Fixes vs r11: NO launch-bounds VGPR cap (the 64-VGPR cap caused f32x16 scratch spill = the
// 148MB FETCH), and bank swizzle upgraded to f(row)=(row&7)^(((row>>3)&3)<<1) so the 4 rows
// aliasing per (row&7) class hit disjoint chunk sets (uniform 8 req/bank).
__global__ __launch_bounds__(256)
void flash32_kernel(const unsigned short* __restrict__ qb, const unsigned short* __restrict__ kb,
                    const unsigned short* __restrict__ vtb, const unsigned long long* __restrict__ mbits,
                    float* __restrict__ opart, float* __restrict__ lsum) {
  __shared__ alignas(16) unsigned short kv[2][2][4096];
  __shared__ alignas(16) f32x4 btab[16];
  const int tid = threadIdx.x;
  const int wave = tid >> 6, lane = tid & 63;
  const int l31 = lane & 31, lh = lane >> 5;
  const int wgid = blockIdx.x;
  const int slot = wgid >> 3;
  const int bh = (wgid & 7) * 4 + (slot & 3);
  const int rest = slot >> 2;            // 0..15 = qchunk
  const int q0 = rest * 128 + wave * 32;
  const int b = bh >> 3, h = bh & 7;
  const unsigned short* Q = qb + ((size_t)bh * S + q0) * HD;
  const unsigned short* Kp = kb + (size_t)bh * S * HD;
  const unsigned short* Vt = vtb + (size_t)bh * HD * S;
  const unsigned long long* Mrow = mbits + ((size_t)b * S + q0 + l31) * (S / 64);  // kh = 0

  const int srow = tid >> 3;             // 0..31; call1 covers rows srow+32
  const int ch = tid & 7;
  const int fst = (srow & 7) ^ (((srow >> 3) & 3) << 1);  // bank-spread swizzle (f(row+32)=f(row))
  const int scol = (ch ^ fst) * 8;
  // K row permutation pi (32x32 layout): so lane's 32 score slots == its PV A-frags
  const int pif = 16 * ((srow >> 4) & 1) + 8 * ((srow >> 2) & 1) + 4 * ((srow >> 3) & 1) + (srow & 3);
  const int wbase = wave * 512;
  const int frd = (l31 & 7) ^ (((l31 >> 3) & 3) << 1);

  if (tid < 16) {
    f32x4 e;
    e[0] = (tid & 1) ? 0.f : -300.f;
    e[1] = (tid & 2) ? 0.f : -300.f;
    e[2] = (tid & 4) ? 0.f : -300.f;
    e[3] = (tid & 8) ? 0.f : -300.f;
    btab[tid] = e;
  }

  bf16x8 qf[4];
#pragma unroll
  for (int wp = 0; wp < 4; ++wp)
    qf[wp] = *(const bf16x8*)&Q[l31 * HD + wp * 16 + 8 * lh];
  f32x16 o0 = {}, o1 = {};
  float lpart = 0.f;
  const int mb = lh * 8;

#define FSTAGE(sb, kn)                                                               \
  do {                                                                               \
    gll16(&Kp[(size_t)((kn) + pif) * HD + scol], &kv[sb][0][wbase]);                 \
    gll16(&Kp[(size_t)((kn) + 32 + pif) * HD + scol], &kv[sb][0][2048 + wbase]);     \
    gll16(&Vt[(size_t)srow * S + (kn) + scol], &kv[sb][1][wbase]);                   \
    gll16(&Vt[(size_t)(srow + 32) * S + (kn) + scol], &kv[sb][1][2048 + wbase]);     \
  } while (0)

  unsigned long long wA = Mrow[0];
  FSTAGE(0, 0);
  asm volatile("s_waitcnt vmcnt(0) lgkmcnt(0)" ::: "memory");
  __syncthreads();

  for (int t = 0; t < 16; ++t) {
    const int cur = t & 1;
    unsigned long long wB = 0;
    if (t + 1 < 16) {
      FSTAGE(cur ^ 1, (t + 1) * KBLK);
      wB = Mrow[t + 1];
    }
    const char* kbp = (const char*)&kv[cur][0][0];
    const char* vbp = (const char*)&kv[cur][1][0];

    // ---- QK^T: lane owns q=l31; 16 k-slots per K-row-chunk ----
    f32x16 sc0 = {}, sc1 = {};
    __builtin_amdgcn_s_setprio(1);
#pragma unroll
    for (int wp = 0; wp < 4; ++wp) {
      const int cs = ((2 * wp + lh) ^ frd) * 16;
      bf16x8 kf0 = *(const bf16x8*)(kbp + l31 * 128 + cs);
      bf16x8 kf1 = *(const bf16x8*)(kbp + (32 + l31) * 128 + cs);
      sc0 = MFMA32(kf0, qf[wp], sc0);
      sc1 = MFMA32(kf1, qf[wp], sc1);
    }
    __builtin_amdgcn_s_setprio(0);

    // ---- p = v_exp(s + bias), grouped per nibble to limit live bias regs ----
    f32x16 pv0, pv1;
#pragma unroll
    for (int g = 0; g < 4; ++g) {
      const int sh = (g == 0) ? 0 : (g == 1) ? 4 : (g == 2) ? 16 : 20;
      const f32x4 e0 = btab[(unsigned)(wA >> (mb + sh)) & 15u];
      const f32x4 e1 = btab[(unsigned)(wA >> (mb + 32 + sh)) & 15u];
#pragma unroll
      for (int j = 0; j < 4; ++j) {
        const int r = 8 * (g >> 1) + 4 * (g & 1) + j;
        pv0[r] = __builtin_amdgcn_exp2f(sc0[r] + e0[j]);
        pv1[r] = __builtin_amdgcn_exp2f(sc1[r] + e1[j]);
      }
    }
    float rs = 0.f;
#pragma unroll
    for (int r = 0; r < 16; ++r) rs += pv0[r] + pv1[r];
    lpart += rs;

    // ---- P -> bf16 A-frags in-register ----
    bf16x8 pf[4];
#pragma unroll
    for (int j = 0; j < 8; ++j) {
      const int rr = (j & 3) + 4 * (j >> 2);
      pf[0][j] = (__bf16)pv0[rr];
      pf[1][j] = (__bf16)pv0[rr + 8];
      pf[2][j] = (__bf16)pv1[rr];
      pf[3][j] = (__bf16)pv1[rr + 8];
    }

    // ---- PV ----
    __builtin_amdgcn_s_setprio(1);
#pragma unroll
    for (int w = 0; w < 4; ++w) {
      const int cs = ((2 * w + lh) ^ frd) * 16;
      bf16x8 vf0 = *(const bf16x8*)(vbp + l31 * 128 + cs);
      bf16x8 vf1 = *(const bf16x8*)(vbp + (32 + l31) * 128 + cs);
      o0 = MFMA32(pf[w], vf0, o0);
      o1 = MFMA32(pf[w], vf1, o1);
    }
    __builtin_amdgcn_s_setprio(0);

    asm volatile("s_waitcnt vmcnt(0)" ::: "memory");
    __syncthreads();
    wA = wB;
  }
#undef FSTAGE

  lpart += __shfl_xor(lpart, 32);
  if (lh == 0) lsum[(size_t)bh * S + q0 + l31] = lpart;
#pragma unroll
  for (int r = 0; r < 16; ++r) {
    const size_t row = (size_t)(b * S + q0 + (r & 3) + 8 * (r >> 2) + 4 * lh) * D + h * HD;
    opart[row + l31] = o0[r];
    opart[row + 32 + l31] = o1[r];
  }
}

// ------------- fused out GEMM: A = (op0+op1)*inv[row][head] cast to bf16 in staging -------------
__global__ __launch_bounds__(256)
void gemm_fused(const float* __restrict__ op0, const float* __restrict__ op1,
                const float* __restrict__ ls0, const float* __restrict__ ls1,
                const unsigned short* __restrict__ Bt, float* __restrict__ C) {
  __shared__ alignas(16) unsigned short ldsA[2][2048];  // [stage][64*32]
  __shared__ alignas(16) unsigned short ldsB[2][4096];  // [stage][128*32]
  __shared__ float invt[512];                           // [row64][head8]
  const int tid = threadIdx.x;
  const int lane = tid & 63, l15 = lane & 15, lg = lane >> 4;
  const int wave = tid >> 6;
  const int m0 = blockIdx.x * 64, n0 = blockIdx.y * 128;
  const int wm = (wave >> 1) * 32, wn = (wave & 1) * 64;
  const int wbase = wave * 512;
  const int grow = tid >> 2, gcol = (tid & 3) * 8;
  const size_t abase = (size_t)(m0 + (tid >> 2)) * 512 + (tid & 3) * 8;
  f32x4 acc[2][4] = {};

  for (int e = tid; e < 512; e += 256) {
    const int row = e >> 3, hh = e & 7;
    const int m = m0 + row;
    const size_t li = ((size_t)((m >> 11) * 8 + hh)) * 2048 + (m & 2047);
    const float l = ls0[li] + ls1[li];
    invt[e] = (l > 0.f) ? 1.f / l : 0.f;
  }

#define BSTAGE(sb, kk)                                                               \
  do {                                                                               \
    gll16(&Bt[(size_t)(n0 + grow) * 512 + (kk) + gcol], &ldsB[sb][wbase]);           \
    gll16(&Bt[(size_t)(n0 + 64 + grow) * 512 + (kk) + gcol], &ldsB[sb][2048 + wbase]);\
  } while (0)

  float4 a0, a1, p0, p1;
#define ALOAD(kk)                                          \
  do {                                                     \
    a0 = *(const float4*)&op0[abase + (kk)];               \
    a1 = *(const float4*)&op0[abase + (kk) + 4];           \
    p0 = *(const float4*)&op1[abase + (kk)];               \
    p1 = *(const float4*)&op1[abase + (kk) + 4];           \
  } while (0)

#define AWRITE(sb, kk)                                                       \
  do {                                                                       \
    const float inv = invt[((tid >> 2) << 3) | ((kk) >> 6)];                 \
    short8 pk;                                                               \
    pk[0] = (short)f2b((a0.x + p0.x) * inv);                                 \
    pk[1] = (short)f2b((a0.y + p0.y) * inv);                                 \
    pk[2] = (short)f2b((a0.z + p0.z) * inv);                                 \
    pk[3] = (short)f2b((a0.w + p0.w) * inv);                                 \
    pk[4] = (short)f2b((a1.x + p1.x) * inv);                                 \
    pk[5] = (short)f2b((a1.y + p1.y) * inv);                                 \
    pk[6] = (short)f2b((a1.z + p1.z) * inv);                                 \
    pk[7] = (short)f2b((a1.w + p1.w) * inv);                                 \
    *(short8*)&ldsA[sb][(tid >> 2) * 32 + (tid & 3) * 8] = pk;               \
  } while (0)

  ALOAD(0);
  BSTAGE(0, 0);
  __syncthreads();          // invt visible; drains A loads + B gll16
  AWRITE(0, 0);
  __syncthreads();          // A(0) visible

  for (int t = 0; t < 16; ++t) {
    const int cur = t & 1;
    const bool have = (t + 1 < 16);
    if (have) { ALOAD((t + 1) * 32); BSTAGE(cur ^ 1, (t + 1) * 32); }
    bf16x8 af[2], bfr[4];
#pragma unroll
    for (int i = 0; i < 2; ++i)
      af[i] = *(const bf16x8*)&ldsA[cur][(wm + i * 16 + l15) * 32 + lg * 8];
#pragma unroll
    for (int j = 0; j < 4; ++j)
      bfr[j] = *(const bf16x8*)&ldsB[cur][(wn + j * 16 + l15) * 32 + lg * 8];
    __builtin_amdgcn_s_setprio(1);
#pragma unroll
    for (int i = 0; i < 2; ++i)
#pragma unroll
      for (int j = 0; j < 4; ++j)
        acc[i][j] = MFMA16(af[i], bfr[j], acc[i][j]);
    __builtin_amdgcn_s_setprio(0);
    asm volatile("s_waitcnt vmcnt(0)" ::: "memory");
    __syncthreads();
    if (have) AWRITE(cur ^ 1, (t + 1) * 32);
    __syncthreads();
  }
#undef BSTAGE
#undef ALOAD
#undef AWRITE

#pragma unroll
  for (int i = 0; i < 2; ++i)
#pragma unroll
    for (int j = 0; j < 4; ++j)
#pragma unroll
      for (int r = 0; r < 4; ++r)
        C[(size_t)(m0 + wm + i * 16 + lg * 4 + r) * 512 + (n0 + wn + j * 16 + l15)] = acc[i][j][r];
}

extern "C" void kernel_launch(void* const* d_in, const int* in_sizes, int n_in,
                              void* d_out, int out_size, void* d_ws, size_t ws_size,
                              hipStream_t stream) {
  const float* x = (const float*)d_in[0];
  const float* cose = (const float*)d_in[1];
  const float* sine = (const float*)d_in[2];
  const int* mask = (const int*)d_in[3];
  const float* wq = (const float*)d_in[4];
  const float* wk = (const float*)d_in[5];
  const float* wv = (const float*)d_in[6];
  const float* wo = (const float*)d_in[7];
  float* out = (float*)d_out;
  char* ws = (char*)d_ws;

  // workspace layout (bytes)
  unsigned short* xb    = (unsigned short*)(ws);                 //  8,388,608  x bf16 [8192][512]
  unsigned short* wqkvT = (unsigned short*)(ws + 8388608);       //  1,572,864  [1536][512]
  unsigned short* woT   = (unsigned short*)(ws + 9961472);       //    524,288  [512][512]
  unsigned short* qpre  = (unsigned short*)(ws + 10485760);      //  8,388,608  [B,H,S,HD] pre-rope
  unsigned short* kpre  = (unsigned short*)(ws + 18874368);      //  8,388,608
  unsigned short* qbh   = (unsigned short*)(ws + 35651584);      //  8,388,608  post-rope
  unsigned short* kbh   = (unsigned short*)(ws + 44040192);      //  8,388,608
  unsigned short* vtb   = (unsigned short*)(ws + 52428800);      //  8,388,608  [B,H,HD,S]
  unsigned long long* mbits = (unsigned long long*)(ws + 60817408);  // 2,097,152
  float* op0 = (float*)(ws + 10485760);   // 16,777,216  (over qpre+kpre; dead when flash runs)
  float* op1 = (float*)(ws + 62914560);   // 16,777,216
  float* ls0 = (float*)(ws + 79691776);   //    262,144
  float* ls1 = (float*)(ws + 79953920);   //    262,144  (ends 80,216,064)

  maskbits_kernel<<<2048, 256, 0, stream>>>(mask, mbits);
  cast_x_kernel<<<4096, 256, 0, stream>>>(x, xb);
  wtrans4_kernel<<<dim3(8, 8, 4), 256, 0, stream>>>(wq, wk, wv, wo, wqkvT, woT);
  gemm2<<<dim3(64, 12), 256, 0, stream>>>(xb, wqkvT, 8192, 1536, 512, nullptr, qpre, kpre, vtb, 1);
  rope_pair_kernel<<<1024, 256, 0, stream>>>(qpre, kpre, cose, sine, qbh, kbh);
  flash32_kernel<<<512, 256, 0, stream>>>(qbh, kbh, vtb, mbits, op0, ls0);   // kh = 0 half
  flash16_kernel<<<512, 512, 0, stream>>>(qbh, kbh, vtb, mbits, op1, ls1);   // kh = 1 half
  gemm_fused<<<dim3(128, 4), 256, 0, stream>>>(op0, op1, ls0, ls1, woT, out);
}

// Round 13
// 122.993 us; speedup vs baseline: 1.4219x; 1.0644x over previous
//
#include <hip/hip_runtime.h>
#include <hip/hip_bf16.h>

typedef __bf16 bf16x8 __attribute__((ext_vector_type(8)));
typedef float f32x4 __attribute__((ext_vector_type(4)));
typedef short short8 __attribute__((ext_vector_type(8)));

#define MFMA16(a, b, c) __builtin_amdgcn_mfma_f32_16x16x32_bf16((a), (b), (c), 0, 0, 0)

static constexpr int S = 2048;
static constexpr int D = 512;
static constexpr int HD = 64;
static constexpr int KBLK = 64;
// q scale: 1/sqrt(HD) * log2(e), so softmax can use exp2
#define QSCALE 0.18033688011112042f

typedef __attribute__((address_space(1))) const unsigned int gu32;
typedef __attribute__((address_space(3))) unsigned int lu32;

__device__ __forceinline__ void gll16(const void* g, void* l) {
  __builtin_amdgcn_global_load_lds((gu32*)g, (lu32*)l, 16, 0, 0);
}

__device__ __forceinline__ unsigned short f2b(float f) {
  return __builtin_bit_cast(unsigned short, __float2bfloat16(f));
}
__device__ __forceinline__ float b2f(unsigned short u) {
  return __builtin_bit_cast(float, (unsigned)u << 16);
}

// ---------------- mask (int32 0/1) -> bitmask [B*S][S/64] u64, grid-stride ----------------
__global__ void maskbits_kernel(const int* __restrict__ m, unsigned long long* __restrict__ bits) {
  const int stride = 2048 * 256;
  const int lane0 = (threadIdx.x & 63) == 0;
  for (int gid = blockIdx.x * 256 + threadIdx.x; gid < 4 * 2048 * 2048; gid += stride) {
    unsigned long long w = __ballot(m[gid] != 0);
    if (lane0) bits[gid >> 6] = w;
  }
}

// ---------------- cast x (f32 -> bf16), 4 elems/thread ----------------
__global__ void cast_x_kernel(const float* __restrict__ x, unsigned short* __restrict__ xb) {
  int idx = blockIdx.x * 256 + threadIdx.x;
  float4 v = ((const float4*)x)[idx];
  ushort4 o;
  o.x = f2b(v.x); o.y = f2b(v.y); o.z = f2b(v.z); o.w = f2b(v.w);
  ((ushort4*)xb)[idx] = o;
}

// ------------- tiled transpose+cast of the 4 weight matrices -------------
__global__ void wtrans4_kernel(const float* __restrict__ wq, const float* __restrict__ wk,
                               const float* __restrict__ wv, const float* __restrict__ wo,
                               unsigned short* __restrict__ wqkvT, unsigned short* __restrict__ woT) {
  __shared__ float t[64][65];
  const int z = blockIdx.z;
  const float* w = (z == 0) ? wq : (z == 1) ? wk : (z == 2) ? wv : wo;
  unsigned short* dst = (z < 3) ? wqkvT + (size_t)z * 512 * 512 : woT;
  const int i0 = blockIdx.x * 64, o0 = blockIdx.y * 64;
  for (int it = 0; it < 16; ++it) {
    int idx = it * 256 + threadIdx.x;
    int ii = idx >> 6, oo = idx & 63;
    t[oo][ii] = w[(size_t)(i0 + ii) * 512 + o0 + oo];
  }
  __syncthreads();
  for (int it = 0; it < 16; ++it) {
    int idx = it * 256 + threadIdx.x;
    int oo = idx >> 6, ii = idx & 63;
    dst[(size_t)(o0 + oo) * 512 + i0 + ii] = f2b(t[oo][ii]);
  }
}

// ------------- GEMM: C = A[M][K] * Bt[N][K]^T, gll16-staged dbuf, 128x128 tile BK=32 -------------
// mode 0: f32 C row-major. mode 1: bf16 per-head scatter: q/k pre-rope [B,H,S,HD]; V TRANSPOSED
// [B,H,HD,S] via per-wave LDS transpose (coalesced 128B row stores; the old 2B/4KB-stride scatter
// was ~16x write-amplified). Staging LDS is dead post-loop, so the transpose buffer unions it.
__global__ __launch_bounds__(256)
void gemm2(const unsigned short* __restrict__ A, const unsigned short* __restrict__ Bt,
           int M, int N, int K, float* __restrict__ Cf,
           unsigned short* __restrict__ qd, unsigned short* __restrict__ kd,
           unsigned short* __restrict__ vtd, int mode) {
  __shared__ alignas(16) unsigned char smem[36864];  // 32KB staging | 36KB V-transpose (union)
  unsigned short (*lds)[2][4096] = (unsigned short (*)[2][4096])smem;
  const int tid = threadIdx.x;
  const int lane = tid & 63, l15 = lane & 15, lg = lane >> 4;
  const int wave = tid >> 6;
  const int m0 = blockIdx.x * 128, n0 = blockIdx.y * 128;
  const int wm = (wave >> 1) * 64, wn = (wave & 1) * 64;
  const int wbase = wave * 512;  // ushort units; gll16 dest is wave-uniform base + lane*16B
  const int grow = tid >> 2, gcol = (tid & 3) * 8;
  f32x4 acc[4][4] = {};
  const int nt = K / 32;

#define GSTAGE(sb, kk)                                                              \
  do {                                                                              \
    gll16(&A[(size_t)(m0 + grow) * K + (kk) + gcol], &lds[sb][0][wbase]);           \
    gll16(&A[(size_t)(m0 + 64 + grow) * K + (kk) + gcol], &lds[sb][0][2048 + wbase]);\
    gll16(&Bt[(size_t)(n0 + grow) * K + (kk) + gcol], &lds[sb][1][wbase]);          \
    gll16(&Bt[(size_t)(n0 + 64 + grow) * K + (kk) + gcol], &lds[sb][1][2048 + wbase]);\
  } while (0)

  GSTAGE(0, 0);
  asm volatile("s_waitcnt vmcnt(0)" ::: "memory");
  __syncthreads();
  for (int t = 0; t < nt; ++t) {
    const int cur = t & 1;
    if (t + 1 < nt) GSTAGE(cur ^ 1, (t + 1) * 32);
    bf16x8 af[4], bfr[4];
#pragma unroll
    for (int i = 0; i < 4; ++i) {
      af[i]  = *(const bf16x8*)&lds[cur][0][(wm + i * 16 + l15) * 32 + lg * 8];
      bfr[i] = *(const bf16x8*)&lds[cur][1][(wn + i * 16 + l15) * 32 + lg * 8];
    }
    __builtin_amdgcn_s_setprio(1);
#pragma unroll
    for (int i = 0; i < 4; ++i)
#pragma unroll
      for (int j = 0; j < 4; ++j)
        acc[i][j] = MFMA16(af[i], bfr[j], acc[i][j]);
    __builtin_amdgcn_s_setprio(0);
    asm volatile("s_waitcnt vmcnt(0)" ::: "memory");
    __syncthreads();
  }
#undef GSTAGE

  if (mode == 0) {
#pragma unroll
    for (int i = 0; i < 4; ++i)
#pragma unroll
      for (int j = 0; j < 4; ++j)
#pragma unroll
        for (int r = 0; r < 4; ++r)
          Cf[(size_t)(m0 + wm + i * 16 + lg * 4 + r) * N + (n0 + wn + j * 16 + l15)] = acc[i][j][r];
  } else {
    const int sel = n0 >> 9;  // block never crosses a 512 boundary
    const int nb = (n0 & 511) + wn;
    if (sel < 2) {
      unsigned short* dst = (sel == 0) ? qd : kd;
#pragma unroll
      for (int i = 0; i < 4; ++i)
#pragma unroll
        for (int j = 0; j < 4; ++j)
#pragma unroll
          for (int r = 0; r < 4; ++r) {
            const int m = m0 + wm + i * 16 + lg * 4 + r;
            const int nn = nb + j * 16 + l15;
            dst[(((size_t)(m >> 11) * 8 + (nn >> 6)) * 2048 + (m & 2047)) * 64 + (nn & 63)] =
                f2b(acc[i][j][r]);
          }
    } else {
      // V transposed via per-wave LDS transpose. tb: 64 rows (nn) x 72 ushorts (16B-aligned pad).
      unsigned short* tb = (unsigned short*)smem + wave * 4608;
#pragma unroll
      for (int i = 0; i < 4; ++i)
#pragma unroll
        for (int j = 0; j < 4; ++j) {
          ushort4 pk;
          pk.x = f2b(acc[i][j][0]); pk.y = f2b(acc[i][j][1]);
          pk.z = f2b(acc[i][j][2]); pk.w = f2b(acc[i][j][3]);
          *(ushort4*)&tb[(j * 16 + l15) * 72 + i * 16 + lg * 4] = pk;
        }
      const int b0 = m0 >> 11;
      const int s0 = (m0 & 2047) + wm;
      const int g = lane >> 3, c = lane & 7;
#pragma unroll
      for (int rr = 0; rr < 8; ++rr) {
        const int row = rr * 8 + g;
        const int nng = nb + row;
        uint4 v = *(const uint4*)&tb[row * 72 + c * 8];
        *(uint4*)&vtd[(((size_t)(b0 * 8) + (nng >> 6)) * 64 + (nng & 63)) * 2048 + s0 + c * 8] = v;
      }
    }
  }
}

// ------------- RoPE, head pair (h, h+4) per thread: each q/k element read ONCE -------------
__global__ void rope_pair_kernel(const unsigned short* __restrict__ qpre, const unsigned short* __restrict__ kpre,
                                 const float* __restrict__ cose, const float* __restrict__ sine,
                                 unsigned short* __restrict__ qb, unsigned short* __restrict__ kb) {
  const int idx = blockIdx.x * 256 + threadIdx.x;  // 0 .. B*4*S*8-1
  const int hd0 = (idx & 7) * 8;
  const int rr = idx >> 3;           // (b*4 + h)*2048 + s, h in 0..3
  const int b = rr >> 13, h = (rr >> 11) & 3, s = rr & 2047;
  const size_t lo = ((size_t)(b * 8 + h) * 2048 + s) * 64 + hd0;
  const size_t hi = lo + (size_t)4 * 2048 * 64;
  const int d0 = h * 64 + hd0;       // < 256
  short8 qlo = *(const short8*)&qpre[lo];
  short8 qhi = *(const short8*)&qpre[hi];
  short8 klo = *(const short8*)&kpre[lo];
  short8 khi = *(const short8*)&kpre[hi];
  float4 c0 = *(const float4*)&cose[(size_t)s * 512 + d0];
  float4 c1 = *(const float4*)&cose[(size_t)s * 512 + d0 + 4];
  float4 s0 = *(const float4*)&sine[(size_t)s * 512 + d0];
  float4 s1 = *(const float4*)&sine[(size_t)s * 512 + d0 + 4];
  float cc[8] = {c0.x, c0.y, c0.z, c0.w, c1.x, c1.y, c1.z, c1.w};
  float ss[8] = {s0.x, s0.y, s0.z, s0.w, s1.x, s1.y, s1.z, s1.w};
  short8 qolo, qohi, kolo, kohi;
#pragma unroll
  for (int j = 0; j < 8; ++j) {
    float ql = b2f((unsigned short)qlo[j]), qh = b2f((unsigned short)qhi[j]);
    float kl = b2f((unsigned short)klo[j]), kh = b2f((unsigned short)khi[j]);
    qolo[j] = (short)f2b((ql * cc[j] - qh * ss[j]) * QSCALE);
    qohi[j] = (short)f2b((qh * cc[j] + ql * ss[j]) * QSCALE);
    kolo[j] = (short)f2b(kl * cc[j] - kh * ss[j]);
    kohi[j] = (short)f2b(kh * cc[j] + kl * ss[j]);
  }
  *(short8*)&qb[lo] = qolo;
  *(short8*)&qb[hi] = qohi;
  *(short8*)&kb[lo] = kolo;
  *(short8*)&kb[hi] = kohi;
}

// ------------- flash attention (r9 proven): split-K, grid 1024 = 8 xcd x 4 bh x 2 kh x 16 qc ----
// 512 thr, 8 waves x 16 q-rows. Un-normalized f32 partials + row-sums. P fully in-register via
// K-row permutation pi; raw v_exp_f32 (FTZ: bias -300 -> exact 0); no running max (log2 domain).
__global__ __launch_bounds__(512)
void flash_kernel(const unsigned short* __restrict__ qb, const unsigned short* __restrict__ kb,
                  const unsigned short* __restrict__ vtb, const unsigned long long* __restrict__ mbits,
                  float* __restrict__ op0, float* __restrict__ op1,
                  float* __restrict__ ls0, float* __restrict__ ls1) {
  __shared__ alignas(16) unsigned short kv[2][2][4096];   // [stage][K|V][64x64 bf16], src-swizzled
  __shared__ alignas(16) f32x4 btab[16];                  // nibble -> bias4 (0 or -300 per bit)
  const int tid = threadIdx.x;
  const int wave = tid >> 6, lane = tid & 63;
  const int l15 = lane & 15, lg = lane >> 4;
  const int swz = (l15 & 7) << 4;
  const int wgid = blockIdx.x;
  const int slot = wgid >> 3;
  const int bh = (wgid & 7) * 4 + (slot & 3);
  const int rest = slot >> 2;            // 0..31
  const int kh = rest & 1;
  const int q0 = (rest >> 1) * 128 + wave * 16;
  const int b = bh >> 3, h = bh & 7;
  const int kbase = kh * 1024;
  const unsigned short* Q = qb + ((size_t)bh * S + q0) * HD;
  const unsigned short* Kp = kb + (size_t)bh * S * HD;
  const unsigned short* Vt = vtb + (size_t)bh * HD * S;
  const unsigned long long* Mrow = mbits + ((size_t)b * S + q0 + l15) * (S / 64) + kh * 16;
  float* opart = kh ? op1 : op0;
  float* lsum = kh ? ls1 : ls0;

  const int srow = tid >> 3;
  const int scol = ((tid & 7) ^ (srow & 7)) * 8;
  const int ksrow = ((srow & 15) >> 2) * 8 + ((srow >> 4) & 1) * 4 + (srow & 3) + (srow >> 5) * 32;
  const int wbase = wave * 512;  // ushort units (wave-uniform)

  if (tid < 16) {
    f32x4 e;
    e[0] = (tid & 1) ? 0.f : -300.f;
    e[1] = (tid & 2) ? 0.f : -300.f;
    e[2] = (tid & 4) ? 0.f : -300.f;
    e[3] = (tid & 8) ? 0.f : -300.f;
    btab[tid] = e;
  }

  bf16x8 qf0 = *(const bf16x8*)&Q[l15 * HD + lg * 8];
  bf16x8 qf1 = *(const bf16x8*)&Q[l15 * HD + 32 + lg * 8];
  f32x4 o[4] = {};
  float lpart = 0.f;  // per-lane partial softmax denominator
  const int lgs8 = lg * 8;

  unsigned long long wA = Mrow[0];
  gll16(&Kp[(size_t)(kbase + ksrow) * HD + scol], &kv[0][0][wbase]);
  gll16(&Vt[(size_t)srow * S + kbase + scol], &kv[0][1][wbase]);
  asm volatile("s_waitcnt vmcnt(0) lgkmcnt(0)" ::: "memory");
  __syncthreads();

  for (int t = 0; t < 16; ++t) {
    const int cur = t & 1;
    unsigned long long wB = 0;
    if (t + 1 < 16) {
      const int kn = kbase + (t + 1) * KBLK;
      gll16(&Kp[(size_t)(kn + ksrow) * HD + scol], &kv[cur ^ 1][0][wbase]);
      gll16(&Vt[(size_t)srow * S + kn + scol], &kv[cur ^ 1][1][wbase]);
      wB = Mrow[t + 1];
    }
    const char* kbp = (const char*)&kv[cur][0][0];
    const char* vbp = (const char*)&kv[cur][1][0];

    f32x4 sc[4] = {};
    __builtin_amdgcn_s_setprio(1);
#pragma unroll
    for (int n = 0; n < 4; ++n) {
      const int cb = (n * 16 + l15) * 128 + ((lg * 16) ^ swz);
      bf16x8 kf0 = *(const bf16x8*)(kbp + cb);
      bf16x8 kf1 = *(const bf16x8*)(kbp + (cb ^ 64));
      sc[n] = MFMA16(kf0, qf0, sc[n]);  // swapped: lane owns q=l15, k=pi(n*16+lg*4+r)
      sc[n] = MFMA16(kf1, qf1, sc[n]);
    }
    __builtin_amdgcn_s_setprio(0);

    // ---- p = v_exp(s + bias); FTZ makes masked (bias -300) exactly 0 ----
    f32x4 pv[4];
    {
      const f32x4 b0 = btab[(unsigned)(wA >> (lgs8 + 0)) & 15u];
      const f32x4 b1 = btab[(unsigned)(wA >> (lgs8 + 4)) & 15u];
      const f32x4 b2 = btab[(unsigned)(wA >> (lgs8 + 32)) & 15u];
      const f32x4 b3 = btab[(unsigned)(wA >> (lgs8 + 36)) & 15u];
#pragma unroll
      for (int r = 0; r < 4; ++r) {
        pv[0][r] = __builtin_amdgcn_exp2f(sc[0][r] + b0[r]);
        pv[1][r] = __builtin_amdgcn_exp2f(sc[1][r] + b1[r]);
        pv[2][r] = __builtin_amdgcn_exp2f(sc[2][r] + b2[r]);
        pv[3][r] = __builtin_amdgcn_exp2f(sc[3][r] + b3[r]);
      }
    }
    f32x4 s4 = (pv[0] + pv[1]) + (pv[2] + pv[3]);
    lpart += (s4[0] + s4[1]) + (s4[2] + s4[3]);

    // ---- P -> bf16 A-frags, fully in-register ----
    bf16x8 pf0, pf1;
#pragma unroll
    for (int j = 0; j < 4; ++j) {
      pf0[j]     = (__bf16)pv[0][j];
      pf0[j + 4] = (__bf16)pv[1][j];
      pf1[j]     = (__bf16)pv[2][j];
      pf1[j + 4] = (__bf16)pv[3][j];
    }

    // ---- PV from LDS V + register P ----
    __builtin_amdgcn_s_setprio(1);
#pragma unroll
    for (int n = 0; n < 4; ++n) {
      const int cb = (n * 16 + l15) * 128 + ((lg * 16) ^ swz);
      bf16x8 vf0 = *(const bf16x8*)(vbp + cb);
      bf16x8 vf1 = *(const bf16x8*)(vbp + (cb ^ 64));
      o[n] = MFMA16(pf0, vf0, o[n]);
      o[n] = MFMA16(pf1, vf1, o[n]);
    }
    __builtin_amdgcn_s_setprio(0);

    asm volatile("s_waitcnt vmcnt(0)" ::: "memory");  // next tile landed
    __syncthreads();
    wA = wB;
  }

  lpart += __shfl_xor(lpart, 16);
  lpart += __shfl_xor(lpart, 32);
  if (lg == 0) lsum[(size_t)bh * S + q0 + l15] = lpart;
#pragma unroll
  for (int r = 0; r < 4; ++r)
#pragma unroll
    for (int n = 0; n < 4; ++n)
      opart[((size_t)(b * S + q0 + lg * 4 + r)) * D + h * HD + n * 16 + l15] = o[n][r];
}

// ------------- fused out GEMM: A = (op0+op1)*inv[row][head] cast to bf16 in staging -------------
__global__ __launch_bounds__(256)
void gemm_fused(const float* __restrict__ op0, const float* __restrict__ op1,
                const float* __restrict__ ls0, const float* __restrict__ ls1,
                const unsigned short* __restrict__ Bt, float* __restrict__ C) {
  __shared__ alignas(16) unsigned short ldsA[2][2048];  // [stage][64*32]
  __shared__ alignas(16) unsigned short ldsB[2][4096];  // [stage][128*32]
  __shared__ float invt[512];                           // [row64][head8]
  const int tid = threadIdx.x;
  const int lane = tid & 63, l15 = lane & 15, lg = lane >> 4;
  const int wave = tid >> 6;
  const int m0 = blockIdx.x * 64, n0 = blockIdx.y * 128;
  const int wm = (wave >> 1) * 32, wn = (wave & 1) * 64;
  const int wbase = wave * 512;
  const int grow = tid >> 2, gcol = (tid & 3) * 8;
  const size_t abase = (size_t)(m0 + (tid >> 2)) * 512 + (tid & 3) * 8;
  f32x4 acc[2][4] = {};

  for (int e = tid; e < 512; e += 256) {
    const int row = e >> 3, hh = e & 7;
    const int m = m0 + row;
    const size_t li = ((size_t)((m >> 11) * 8 + hh)) * 2048 + (m & 2047);
    const float l = ls0[li] + ls1[li];
    invt[e] = (l > 0.f) ? 1.f / l : 0.f;
  }

#define BSTAGE(sb, kk)                                                               \
  do {                                                                               \
    gll16(&Bt[(size_t)(n0 + grow) * 512 + (kk) + gcol], &ldsB[sb][wbase]);           \
    gll16(&Bt[(size_t)(n0 + 64 + grow) * 512 + (kk) + gcol], &ldsB[sb][2048 + wbase]);\
  } while (0)

  float4 a0, a1, p0, p1;
#define ALOAD(kk)                                          \
  do {                                                     \
    a0 = *(const float4*)&op0[abase + (kk)];               \
    a1 = *(const float4*)&op0[abase + (kk) + 4];           \
    p0 = *(const float4*)&op1[abase + (kk)];               \
    p1 = *(const float4*)&op1[abase + (kk) + 4];           \
  } while (0)

#define AWRITE(sb, kk)                                                       \
  do {                                                                       \
    const float inv = invt[((tid >> 2) << 3) | ((kk) >> 6)];                 \
    short8 pk;                                                               \
    pk[0] = (short)f2b((a0.x + p0.x) * inv);                                 \
    pk[1] = (short)f2b((a0.y + p0.y) * inv);                                 \
    pk[2] = (short)f2b((a0.z + p0.z) * inv);                                 \
    pk[3] = (short)f2b((a0.w + p0.w) * inv);                                 \
    pk[4] = (short)f2b((a1.x + p1.x) * inv);                                 \
    pk[5] = (short)f2b((a1.y + p1.y) * inv);                                 \
    pk[6] = (short)f2b((a1.z + p1.z) * inv);                                 \
    pk[7] = (short)f2b((a1.w + p1.w) * inv);                                 \
    *(short8*)&ldsA[sb][(tid >> 2) * 32 + (tid & 3) * 8] = pk;               \
  } while (0)

  ALOAD(0);
  BSTAGE(0, 0);
  __syncthreads();          // invt visible; drains A loads + B gll16
  AWRITE(0, 0);
  __syncthreads();          // A(0) visible

  for (int t = 0; t < 16; ++t) {
    const int cur = t & 1;
    const bool have = (t + 1 < 16);
    if (have) { ALOAD((t + 1) * 32); BSTAGE(cur ^ 1, (t + 1) * 32); }
    bf16x8 af[2], bfr[4];
#pragma unroll
    for (int i = 0; i < 2; ++i)
      af[i] = *(const bf16x8*)&ldsA[cur][(wm + i * 16 + l15) * 32 + lg * 8];
#pragma unroll
    for (int j = 0; j < 4; ++j)
      bfr[j] = *(const bf16x8*)&ldsB[cur][(wn + j * 16 + l15) * 32 + lg * 8];
    __builtin_amdgcn_s_setprio(1);
#pragma unroll
    for (int i = 0; i < 2; ++i)
#pragma unroll
      for (int j = 0; j < 4; ++j)
        acc[i][j] = MFMA16(af[i], bfr[j], acc[i][j]);
    __builtin_amdgcn_s_setprio(0);
    asm volatile("s_waitcnt vmcnt(0)" ::: "memory");
    __syncthreads();
    if (have) AWRITE(cur ^ 1, (t + 1) * 32);
    __syncthreads();
  }
#undef BSTAGE
#undef ALOAD
#undef AWRITE

#pragma unroll
  for (int i = 0; i < 2; ++i)
#pragma unroll
    for (int j = 0; j < 4; ++j)
#pragma unroll
      for (int r = 0; r < 4; ++r)
        C[(size_t)(m0 + wm + i * 16 + lg * 4 + r) * 512 + (n0 + wn + j * 16 + l15)] = acc[i][j][r];
}

extern "C" void kernel_launch(void* const* d_in, const int* in_sizes, int n_in,
                              void* d_out, int out_size, void* d_ws, size_t ws_size,
                              hipStream_t stream) {
  const float* x = (const float*)d_in[0];
  const float* cose = (const float*)d_in[1];
  const float* sine = (const float*)d_in[2];
  const int* mask = (const int*)d_in[3];
  const float* wq = (const float*)d_in[4];
  const float* wk = (const float*)d_in[5];
  const float* wv = (const float*)d_in[6];
  const float* wo = (const float*)d_in[7];
  float* out = (float*)d_out;
  char* ws = (char*)d_ws;

  // workspace layout (bytes)
  unsigned short* xb    = (unsigned short*)(ws);                 //  8,388,608  x bf16 [8192][512]
  unsigned short* wqkvT = (unsigned short*)(ws + 8388608);       //  1,572,864  [1536][512]
  unsigned short* woT   = (unsigned short*)(ws + 9961472);       //    524,288  [512][512]
  unsigned short* qpre  = (unsigned short*)(ws + 10485760);      //  8,388,608  [B,H,S,HD] pre-rope
  unsigned short* kpre  = (unsigned short*)(ws + 18874368);      //  8,388,608
  unsigned short* qbh   = (unsigned short*)(ws + 35651584);      //  8,388,608  post-rope
  unsigned short* kbh   = (unsigned short*)(ws + 44040192);      //  8,388,608
  unsigned short* vtb   = (unsigned short*)(ws + 52428800);      //  8,388,608  [B,H,HD,S]
  unsigned long long* mbits = (unsigned long long*)(ws + 60817408);  // 2,097,152
  float* op0 = (float*)(ws + 10485760);   // 16,777,216  (over qpre+kpre; dead when flash runs)
  float* op1 = (float*)(ws + 62914560);   // 16,777,216
  float* ls0 = (float*)(ws + 79691776);   //    262,144
  float* ls1 = (float*)(ws + 79953920);   //    262,144  (ends 80,216,064)

  maskbits_kernel<<<2048, 256, 0, stream>>>(mask, mbits);
  cast_x_kernel<<<4096, 256, 0, stream>>>(x, xb);
  wtrans4_kernel<<<dim3(8, 8, 4), 256, 0, stream>>>(wq, wk, wv, wo, wqkvT, woT);
  gemm2<<<dim3(64, 12), 256, 0, stream>>>(xb, wqkvT, 8192, 1536, 512, nullptr, qpre, kpre, vtb, 1);
  rope_pair_kernel<<<1024, 256, 0, stream>>>(qpre, kpre, cose, sine, qbh, kbh);
  flash_kernel<<<1024, 512, 0, stream>>>(qbh, kbh, vtb, mbits, op0, op1, ls0, ls1);
  gemm_fused<<<dim3(128, 4), 256, 0, stream>>>(op0, op1, ls0, ls1, woT, out);
}

// Round 14
// 115.626 us; speedup vs baseline: 1.5125x; 1.0637x over previous
//
#include <hip/hip_runtime.h>
#include <hip/hip_bf16.h>

typedef __bf16 bf16x8 __attribute__((ext_vector_type(8)));
typedef float f32x4 __attribute__((ext_vector_type(4)));
typedef short short8 __attribute__((ext_vector_type(8)));

#define MFMA16(a, b, c) __builtin_amdgcn_mfma_f32_16x16x32_bf16((a), (b), (c), 0, 0, 0)

static constexpr int S = 2048;
static constexpr int D = 512;
static constexpr int HD = 64;
static constexpr int KBLK = 64;
// q scale: 1/sqrt(HD) * log2(e), so softmax can use exp2
#define QSCALE 0.18033688011112042f

typedef __attribute__((address_space(1))) const unsigned int gu32;
typedef __attribute__((address_space(3))) unsigned int lu32;

__device__ __forceinline__ void gll16(const void* g, void* l) {
  __builtin_amdgcn_global_load_lds((gu32*)g, (lu32*)l, 16, 0, 0);
}

__device__ __forceinline__ unsigned short f2b(float f) {
  return __builtin_bit_cast(unsigned short, __float2bfloat16(f));
}
__device__ __forceinline__ float b2f(unsigned short u) {
  return __builtin_bit_cast(float, (unsigned)u << 16);
}

// ------------- merged prep: [0,4096) cast_x | [4096,6144) maskbits | [6144,6400) wtrans4 -------------
__global__ void prep_kernel(const float* __restrict__ x, unsigned short* __restrict__ xb,
                            const int* __restrict__ m, unsigned long long* __restrict__ bits,
                            const float* __restrict__ wq, const float* __restrict__ wk,
                            const float* __restrict__ wv, const float* __restrict__ wo,
                            unsigned short* __restrict__ wqkvT, unsigned short* __restrict__ woT) {
  __shared__ float t[64][65];
  const int blk = blockIdx.x;
  const int tid = threadIdx.x;
  if (blk < 4096) {
    // cast x (f32 -> bf16), 4 elems/thread
    int idx = blk * 256 + tid;
    float4 v = ((const float4*)x)[idx];
    ushort4 o;
    o.x = f2b(v.x); o.y = f2b(v.y); o.z = f2b(v.z); o.w = f2b(v.w);
    ((ushort4*)xb)[idx] = o;
  } else if (blk < 6144) {
    // mask (int32 0/1) -> bitmask, grid-stride over 16.7M elems
    const int stride = 2048 * 256;
    const int lane0 = (tid & 63) == 0;
    for (int gid = (blk - 4096) * 256 + tid; gid < 4 * 2048 * 2048; gid += stride) {
      unsigned long long w = __ballot(m[gid] != 0);
      if (lane0) bits[gid >> 6] = w;
    }
  } else {
    // tiled transpose+cast of the 4 weight matrices
    const int tt = blk - 6144;          // 0..255
    const int z = tt >> 6, r = tt & 63;
    const float* w = (z == 0) ? wq : (z == 1) ? wk : (z == 2) ? wv : wo;
    unsigned short* dst = (z < 3) ? wqkvT + (size_t)z * 512 * 512 : woT;
    const int i0 = (r & 7) * 64, o0 = (r >> 3) * 64;
    for (int it = 0; it < 16; ++it) {
      int idx = it * 256 + tid;
      int ii = idx >> 6, oo = idx & 63;
      t[oo][ii] = w[(size_t)(i0 + ii) * 512 + o0 + oo];
    }
    __syncthreads();
    for (int it = 0; it < 16; ++it) {
      int idx = it * 256 + tid;
      int oo = idx >> 6, ii = idx & 63;
      dst[(size_t)(o0 + oo) * 512 + i0 + ii] = f2b(t[oo][ii]);
    }
  }
}

// ------------- GEMM: C = A[M][K] * Bt[N][K]^T, gll16-staged dbuf, 128x128 tile BK=32 -------------
// mode 0: f32 C row-major. mode 1: bf16 per-head scatter: q/k pre-rope [B,H,S,HD]; V TRANSPOSED
// [B,H,HD,S] via per-wave LDS transpose (coalesced 128B row stores).
__global__ __launch_bounds__(256)
void gemm2(const unsigned short* __restrict__ A, const unsigned short* __restrict__ Bt,
           int M, int N, int K, float* __restrict__ Cf,
           unsigned short* __restrict__ qd, unsigned short* __restrict__ kd,
           unsigned short* __restrict__ vtd, int mode) {
  __shared__ alignas(16) unsigned char smem[36864];  // 32KB staging | 36KB V-transpose (union)
  unsigned short (*lds)[2][4096] = (unsigned short (*)[2][4096])smem;
  const int tid = threadIdx.x;
  const int lane = tid & 63, l15 = lane & 15, lg = lane >> 4;
  const int wave = tid >> 6;
  const int m0 = blockIdx.x * 128, n0 = blockIdx.y * 128;
  const int wm = (wave >> 1) * 64, wn = (wave & 1) * 64;
  const int wbase = wave * 512;  // ushort units; gll16 dest is wave-uniform base + lane*16B
  const int grow = tid >> 2, gcol = (tid & 3) * 8;
  f32x4 acc[4][4] = {};
  const int nt = K / 32;

#define GSTAGE(sb, kk)                                                              \
  do {                                                                              \
    gll16(&A[(size_t)(m0 + grow) * K + (kk) + gcol], &lds[sb][0][wbase]);           \
    gll16(&A[(size_t)(m0 + 64 + grow) * K + (kk) + gcol], &lds[sb][0][2048 + wbase]);\
    gll16(&Bt[(size_t)(n0 + grow) * K + (kk) + gcol], &lds[sb][1][wbase]);          \
    gll16(&Bt[(size_t)(n0 + 64 + grow) * K + (kk) + gcol], &lds[sb][1][2048 + wbase]);\
  } while (0)

  GSTAGE(0, 0);
  asm volatile("s_waitcnt vmcnt(0)" ::: "memory");
  __syncthreads();
  for (int t = 0; t < nt; ++t) {
    const int cur = t & 1;
    if (t + 1 < nt) GSTAGE(cur ^ 1, (t + 1) * 32);
    bf16x8 af[4], bfr[4];
#pragma unroll
    for (int i = 0; i < 4; ++i) {
      af[i]  = *(const bf16x8*)&lds[cur][0][(wm + i * 16 + l15) * 32 + lg * 8];
      bfr[i] = *(const bf16x8*)&lds[cur][1][(wn + i * 16 + l15) * 32 + lg * 8];
    }
    __builtin_amdgcn_s_setprio(1);
#pragma unroll
    for (int i = 0; i < 4; ++i)
#pragma unroll
      for (int j = 0; j < 4; ++j)
        acc[i][j] = MFMA16(af[i], bfr[j], acc[i][j]);
    __builtin_amdgcn_s_setprio(0);
    asm volatile("s_waitcnt vmcnt(0)" ::: "memory");
    __syncthreads();
  }
#undef GSTAGE

  if (mode == 0) {
#pragma unroll
    for (int i = 0; i < 4; ++i)
#pragma unroll
      for (int j = 0; j < 4; ++j)
#pragma unroll
        for (int r = 0; r < 4; ++r)
          Cf[(size_t)(m0 + wm + i * 16 + lg * 4 + r) * N + (n0 + wn + j * 16 + l15)] = acc[i][j][r];
  } else {
    const int sel = n0 >> 9;  // block never crosses a 512 boundary
    const int nb = (n0 & 511) + wn;
    if (sel < 2) {
      unsigned short* dst = (sel == 0) ? qd : kd;
#pragma unroll
      for (int i = 0; i < 4; ++i)
#pragma unroll
        for (int j = 0; j < 4; ++j)
#pragma unroll
          for (int r = 0; r < 4; ++r) {
            const int m = m0 + wm + i * 16 + lg * 4 + r;
            const int nn = nb + j * 16 + l15;
            dst[(((size_t)(m >> 11) * 8 + (nn >> 6)) * 2048 + (m & 2047)) * 64 + (nn & 63)] =
                f2b(acc[i][j][r]);
          }
    } else {
      // V transposed via per-wave LDS transpose. tb: 64 rows (nn) x 72 ushorts.
      unsigned short* tb = (unsigned short*)smem + wave * 4608;
#pragma unroll
      for (int i = 0; i < 4; ++i)
#pragma unroll
        for (int j = 0; j < 4; ++j) {
          ushort4 pk;
          pk.x = f2b(acc[i][j][0]); pk.y = f2b(acc[i][j][1]);
          pk.z = f2b(acc[i][j][2]); pk.w = f2b(acc[i][j][3]);
          *(ushort4*)&tb[(j * 16 + l15) * 72 + i * 16 + lg * 4] = pk;
        }
      const int b0 = m0 >> 11;
      const int s0 = (m0 & 2047) + wm;
      const int g = lane >> 3, c = lane & 7;
#pragma unroll
      for (int rr = 0; rr < 8; ++rr) {
        const int row = rr * 8 + g;
        const int nng = nb + row;
        uint4 v = *(const uint4*)&tb[row * 72 + c * 8];
        *(uint4*)&vtd[(((size_t)(b0 * 8) + (nng >> 6)) * 64 + (nng & 63)) * 2048 + s0 + c * 8] = v;
      }
    }
  }
}

// ------------- RoPE, head pair (h, h+4) per thread: each q/k element read ONCE -------------
__global__ void rope_pair_kernel(const unsigned short* __restrict__ qpre, const unsigned short* __restrict__ kpre,
                                 const float* __restrict__ cose, const float* __restrict__ sine,
                                 unsigned short* __restrict__ qb, unsigned short* __restrict__ kb) {
  const int idx = blockIdx.x * 256 + threadIdx.x;  // 0 .. B*4*S*8-1
  const int hd0 = (idx & 7) * 8;
  const int rr = idx >> 3;           // (b*4 + h)*2048 + s, h in 0..3
  const int b = rr >> 13, h = (rr >> 11) & 3, s = rr & 2047;
  const size_t lo = ((size_t)(b * 8 + h) * 2048 + s) * 64 + hd0;
  const size_t hi = lo + (size_t)4 * 2048 * 64;
  const int d0 = h * 64 + hd0;       // < 256
  short8 qlo = *(const short8*)&qpre[lo];
  short8 qhi = *(const short8*)&qpre[hi];
  short8 klo = *(const short8*)&kpre[lo];
  short8 khi = *(const short8*)&kpre[hi];
  float4 c0 = *(const float4*)&cose[(size_t)s * 512 + d0];
  float4 c1 = *(const float4*)&cose[(size_t)s * 512 + d0 + 4];
  float4 s0 = *(const float4*)&sine[(size_t)s * 512 + d0];
  float4 s1 = *(const float4*)&sine[(size_t)s * 512 + d0 + 4];
  float cc[8] = {c0.x, c0.y, c0.z, c0.w, c1.x, c1.y, c1.z, c1.w};
  float ss[8] = {s0.x, s0.y, s0.z, s0.w, s1.x, s1.y, s1.z, s1.w};
  short8 qolo, qohi, kolo, kohi;
#pragma unroll
  for (int j = 0; j < 8; ++j) {
    float ql = b2f((unsigned short)qlo[j]), qh = b2f((unsigned short)qhi[j]);
    float kl = b2f((unsigned short)klo[j]), kh = b2f((unsigned short)khi[j]);
    qolo[j] = (short)f2b((ql * cc[j] - qh * ss[j]) * QSCALE);
    qohi[j] = (short)f2b((qh * cc[j] + ql * ss[j]) * QSCALE);
    kolo[j] = (short)f2b(kl * cc[j] - kh * ss[j]);
    kohi[j] = (short)f2b(kh * cc[j] + kl * ss[j]);
  }
  *(short8*)&qb[lo] = qolo;
  *(short8*)&qb[hi] = qohi;
  *(short8*)&kb[lo] = kolo;
  *(short8*)&kb[hi] = kohi;
}

// ------------- flash attention: 2 q-chunks per wave sharing every K/V LDS read -------------
// grid 512 = 8 xcd x 4 bh x 2 kh x 8 qchunk; 512 thr, 8 waves. Wave handles q-rows
// [q0,q0+16) and [q0+128,q0+144); kf/vf loaded once, used by both chunks' MFMAs (LDS
// bytes and stage/barrier cost per score HALVED vs r9). Per-n folded softmax keeps the
// live set ~100 VGPR (scA/scB die into pf halves each n). P in-register via pi; raw
// v_exp (FTZ: bias -300 -> exact 0); no running max (log2 domain).
__global__ __launch_bounds__(512)
void flash_kernel(const unsigned short* __restrict__ qb, const unsigned short* __restrict__ kb,
                  const unsigned short* __restrict__ vtb, const unsigned long long* __restrict__ mbits,
                  float* __restrict__ op0, float* __restrict__ op1,
                  float* __restrict__ ls0, float* __restrict__ ls1) {
  __shared__ alignas(16) unsigned short kv[2][2][4096];   // [stage][K|V][64x64 bf16], src-swizzled
  __shared__ alignas(16) f32x4 btab[16];                  // nibble -> bias4 (0 or -300 per bit)
  const int tid = threadIdx.x;
  const int wave = tid >> 6, lane = tid & 63;
  const int l15 = lane & 15, lg = lane >> 4;
  const int swz = (l15 & 7) << 4;
  const int wgid = blockIdx.x;
  const int slot = wgid >> 3;                   // 0..63
  const int bh = (wgid & 7) * 4 + (slot & 3);
  const int rest = slot >> 2;                   // 0..15
  const int kh = rest & 1;
  const int q0 = (rest >> 1) * 256 + wave * 16; // chunk A; chunk B at +128
  const int b = bh >> 3, h = bh & 7;
  const int kbase = kh * 1024;
  const unsigned short* Q = qb + ((size_t)bh * S + q0) * HD;
  const unsigned short* Kp = kb + (size_t)bh * S * HD;
  const unsigned short* Vt = vtb + (size_t)bh * HD * S;
  const unsigned long long* MrowA = mbits + ((size_t)b * S + q0 + l15) * (S / 64) + kh * 16;
  const unsigned long long* MrowB = MrowA + (size_t)128 * (S / 64);
  float* opart = kh ? op1 : op0;
  float* lsum = kh ? ls1 : ls0;

  const int srow = tid >> 3;
  const int scol = ((tid & 7) ^ (srow & 7)) * 8;
  const int ksrow = ((srow & 15) >> 2) * 8 + ((srow >> 4) & 1) * 4 + (srow & 3) + (srow >> 5) * 32;
  const int wbase = wave * 512;  // ushort units (wave-uniform)

  if (tid < 16) {
    f32x4 e;
    e[0] = (tid & 1) ? 0.f : -300.f;
    e[1] = (tid & 2) ? 0.f : -300.f;
    e[2] = (tid & 4) ? 0.f : -300.f;
    e[3] = (tid & 8) ? 0.f : -300.f;
    btab[tid] = e;
  }

  bf16x8 qf0a = *(const bf16x8*)&Q[l15 * HD + lg * 8];
  bf16x8 qf1a = *(const bf16x8*)&Q[l15 * HD + 32 + lg * 8];
  bf16x8 qf0b = *(const bf16x8*)&Q[(128 + l15) * HD + lg * 8];
  bf16x8 qf1b = *(const bf16x8*)&Q[(128 + l15) * HD + 32 + lg * 8];
  f32x4 oa[4] = {}, ob[4] = {};
  float lpa = 0.f, lpb = 0.f;
  const int lgs8 = lg * 8;

  unsigned long long wAa = MrowA[0], wAb = MrowB[0];
  gll16(&Kp[(size_t)(kbase + ksrow) * HD + scol], &kv[0][0][wbase]);
  gll16(&Vt[(size_t)srow * S + kbase + scol], &kv[0][1][wbase]);
  asm volatile("s_waitcnt vmcnt(0) lgkmcnt(0)" ::: "memory");
  __syncthreads();

  for (int t = 0; t < 16; ++t) {
    const int cur = t & 1;
    unsigned long long wBa = 0, wBb = 0;
    if (t + 1 < 16) {
      const int kn = kbase + (t + 1) * KBLK;
      gll16(&Kp[(size_t)(kn + ksrow) * HD + scol], &kv[cur ^ 1][0][wbase]);
      gll16(&Vt[(size_t)srow * S + kn + scol], &kv[cur ^ 1][1][wbase]);
      wBa = MrowA[t + 1];
      wBb = MrowB[t + 1];
    }
    const char* kbp = (const char*)&kv[cur][0][0];
    const char* vbp = (const char*)&kv[cur][1][0];

    // ---- per-n: QK (shared kf) -> folded softmax -> pf halves; scA/scB die each n ----
    bf16x8 pf0a, pf1a, pf0b, pf1b;
#pragma unroll
    for (int n = 0; n < 4; ++n) {
      const int cb = (n * 16 + l15) * 128 + ((lg * 16) ^ swz);
      bf16x8 kf0 = *(const bf16x8*)(kbp + cb);
      bf16x8 kf1 = *(const bf16x8*)(kbp + (cb ^ 64));
      f32x4 scA = {}, scB = {};
      __builtin_amdgcn_s_setprio(1);
      scA = MFMA16(kf0, qf0a, scA);  // swapped: lane owns q=l15, k=pi(n*16+lg*4+r)
      scA = MFMA16(kf1, qf1a, scA);
      scB = MFMA16(kf0, qf0b, scB);
      scB = MFMA16(kf1, qf1b, scB);
      __builtin_amdgcn_s_setprio(0);
      const int sh = (n == 0) ? 0 : (n == 1) ? 4 : (n == 2) ? 32 : 36;
      const f32x4 ba = btab[(unsigned)(wAa >> (lgs8 + sh)) & 15u];
      const f32x4 bb = btab[(unsigned)(wAb >> (lgs8 + sh)) & 15u];
      f32x4 pa, pb;
#pragma unroll
      for (int r = 0; r < 4; ++r) {
        pa[r] = __builtin_amdgcn_exp2f(scA[r] + ba[r]);
        pb[r] = __builtin_amdgcn_exp2f(scB[r] + bb[r]);
      }
      lpa += (pa[0] + pa[1]) + (pa[2] + pa[3]);
      lpb += (pb[0] + pb[1]) + (pb[2] + pb[3]);
      bf16x8& dsta = (n < 2) ? pf0a : pf1a;
      bf16x8& dstb = (n < 2) ? pf0b : pf1b;
      const int jo = (n & 1) * 4;
#pragma unroll
      for (int j = 0; j < 4; ++j) {
        dsta[jo + j] = (__bf16)pa[j];
        dstb[jo + j] = (__bf16)pb[j];
      }
    }

    // ---- PV (shared vf): oa/ob += P x V ----
    __builtin_amdgcn_s_setprio(1);
#pragma unroll
    for (int n = 0; n < 4; ++n) {
      const int cb = (n * 16 + l15) * 128 + ((lg * 16) ^ swz);
      bf16x8 vf0 = *(const bf16x8*)(vbp + cb);
      bf16x8 vf1 = *(const bf16x8*)(vbp + (cb ^ 64));
      oa[n] = MFMA16(pf0a, vf0, oa[n]);
      oa[n] = MFMA16(pf1a, vf1, oa[n]);
      ob[n] = MFMA16(pf0b, vf0, ob[n]);
      ob[n] = MFMA16(pf1b, vf1, ob[n]);
    }
    __builtin_amdgcn_s_setprio(0);

    asm volatile("s_waitcnt vmcnt(0)" ::: "memory");  // next tile landed
    __syncthreads();
    wAa = wBa;
    wAb = wBb;
  }

  lpa += __shfl_xor(lpa, 16);
  lpa += __shfl_xor(lpa, 32);
  lpb += __shfl_xor(lpb, 16);
  lpb += __shfl_xor(lpb, 32);
  if (lg == 0) {
    lsum[(size_t)bh * S + q0 + l15] = lpa;
    lsum[(size_t)bh * S + q0 + 128 + l15] = lpb;
  }
#pragma unroll
  for (int r = 0; r < 4; ++r)
#pragma unroll
    for (int n = 0; n < 4; ++n) {
      opart[((size_t)(b * S + q0 + lg * 4 + r)) * D + h * HD + n * 16 + l15] = oa[n][r];
      opart[((size_t)(b * S + q0 + 128 + lg * 4 + r)) * D + h * HD + n * 16 + l15] = ob[n][r];
    }
}

// ------------- fused out GEMM: A = (op0+op1)*inv[row][head] cast to bf16 in staging -------------
__global__ __launch_bounds__(256)
void gemm_fused(const float* __restrict__ op0, const float* __restrict__ op1,
                const float* __restrict__ ls0, const float* __restrict__ ls1,
                const unsigned short* __restrict__ Bt, float* __restrict__ C) {
  __shared__ alignas(16) unsigned short ldsA[2][2048];  // [stage][64*32]
  __shared__ alignas(16) unsigned short ldsB[2][4096];  // [stage][128*32]
  __shared__ float invt[512];                           // [row64][head8]
  const int tid = threadIdx.x;
  const int lane = tid & 63, l15 = lane & 15, lg = lane >> 4;
  const int wave = tid >> 6;
  const int m0 = blockIdx.x * 64, n0 = blockIdx.y * 128;
  const int wm = (wave >> 1) * 32, wn = (wave & 1) * 64;
  const int wbase = wave * 512;
  const int grow = tid >> 2, gcol = (tid & 3) * 8;
  const size_t abase = (size_t)(m0 + (tid >> 2)) * 512 + (tid & 3) * 8;
  f32x4 acc[2][4] = {};

  for (int e = tid; e < 512; e += 256) {
    const int row = e >> 3, hh = e & 7;
    const int m = m0 + row;
    const size_t li = ((size_t)((m >> 11) * 8 + hh)) * 2048 + (m & 2047);
    const float l = ls0[li] + ls1[li];
    invt[e] = (l > 0.f) ? 1.f / l : 0.f;
  }

#define BSTAGE(sb, kk)                                                               \
  do {                                                                               \
    gll16(&Bt[(size_t)(n0 + grow) * 512 + (kk) + gcol], &ldsB[sb][wbase]);           \
    gll16(&Bt[(size_t)(n0 + 64 + grow) * 512 + (kk) + gcol], &ldsB[sb][2048 + wbase]);\
  } while (0)

  float4 a0, a1, p0, p1;
#define ALOAD(kk)                                          \
  do {                                                     \
    a0 = *(const float4*)&op0[abase + (kk)];               \
    a1 = *(const float4*)&op0[abase + (kk) + 4];           \
    p0 = *(const float4*)&op1[abase + (kk)];               \
    p1 = *(const float4*)&op1[abase + (kk) + 4];           \
  } while (0)

#define AWRITE(sb, kk)                                                       \
  do {                                                                       \
    const float inv = invt[((tid >> 2) << 3) | ((kk) >> 6)];                 \
    short8 pk;                                                               \
    pk[0] = (short)f2b((a0.x + p0.x) * inv);                                 \
    pk[1] = (short)f2b((a0.y + p0.y) * inv);                                 \
    pk[2] = (short)f2b((a0.z + p0.z) * inv);                                 \
    pk[3] = (short)f2b((a0.w + p0.w) * inv);                                 \
    pk[4] = (short)f2b((a1.x + p1.x) * inv);                                 \
    pk[5] = (short)f2b((a1.y + p1.y) * inv);                                 \
    pk[6] = (short)f2b((a1.z + p1.z) * inv);                                 \
    pk[7] = (short)f2b((a1.w + p1.w) * inv);                                 \
    *(short8*)&ldsA[sb][(tid >> 2) * 32 + (tid & 3) * 8] = pk;               \
  } while (0)

  ALOAD(0);
  BSTAGE(0, 0);
  __syncthreads();          // invt visible; drains A loads + B gll16
  AWRITE(0, 0);
  __syncthreads();          // A(0) visible

  for (int t = 0; t < 16; ++t) {
    const int cur = t & 1;
    const bool have = (t + 1 < 16);
    if (have) { ALOAD((t + 1) * 32); BSTAGE(cur ^ 1, (t + 1) * 32); }
    bf16x8 af[2], bfr[4];
#pragma unroll
    for (int i = 0; i < 2; ++i)
      af[i] = *(const bf16x8*)&ldsA[cur][(wm + i * 16 + l15) * 32 + lg * 8];
#pragma unroll
    for (int j = 0; j < 4; ++j)
      bfr[j] = *(const bf16x8*)&ldsB[cur][(wn + j * 16 + l15) * 32 + lg * 8];
    __builtin_amdgcn_s_setprio(1);
#pragma unroll
    for (int i = 0; i < 2; ++i)
#pragma unroll
      for (int j = 0; j < 4; ++j)
        acc[i][j] = MFMA16(af[i], bfr[j], acc[i][j]);
    __builtin_amdgcn_s_setprio(0);
    asm volatile("s_waitcnt vmcnt(0)" ::: "memory");
    __syncthreads();
    if (have) AWRITE(cur ^ 1, (t + 1) * 32);
    __syncthreads();
  }
#undef BSTAGE
#undef ALOAD
#undef AWRITE

#pragma unroll
  for (int i = 0; i < 2; ++i)
#pragma unroll
    for (int j = 0; j < 4; ++j)
#pragma unroll
      for (int r = 0; r < 4; ++r)
        C[(size_t)(m0 + wm + i * 16 + lg * 4 + r) * 512 + (n0 + wn + j * 16 + l15)] = acc[i][j][r];
}

extern "C" void kernel_launch(void* const* d_in, const int* in_sizes, int n_in,
                              void* d_out, int out_size, void* d_ws, size_t ws_size,
                              hipStream_t stream) {
  const float* x = (const float*)d_in[0];
  const float* cose = (const float*)d_in[1];
  const float* sine = (const float*)d_in[2];
  const int* mask = (const int*)d_in[3];
  const float* wq = (const float*)d_in[4];
  const float* wk = (const float*)d_in[5];
  const float* wv = (const float*)d_in[6];
  const float* wo = (const float*)d_in[7];
  float* out = (float*)d_out;
  char* ws = (char*)d_ws;

  // workspace layout (bytes)
  unsigned short* xb    = (unsigned short*)(ws);                 //  8,388,608  x bf16 [8192][512]
  unsigned short* wqkvT = (unsigned short*)(ws + 8388608);       //  1,572,864  [1536][512]
  unsigned short* woT   = (unsigned short*)(ws + 9961472);       //    524,288  [512][512]
  unsigned short* qpre  = (unsigned short*)(ws + 10485760);      //  8,388,608  [B,H,S,HD] pre-rope
  unsigned short* kpre  = (unsigned short*)(ws + 18874368);      //  8,388,608
  unsigned short* qbh   = (unsigned short*)(ws + 35651584);      //  8,388,608  post-rope
  unsigned short* kbh   = (unsigned short*)(ws + 44040192);      //  8,388,608
  unsigned short* vtb   = (unsigned short*)(ws + 52428800);      //  8,388,608  [B,H,HD,S]
  unsigned long long* mbits = (unsigned long long*)(ws + 60817408);  // 2,097,152
  float* op0 = (float*)(ws + 10485760);   // 16,777,216  (over qpre+kpre; dead when flash runs)
  float* op1 = (float*)(ws + 62914560);   // 16,777,216
  float* ls0 = (float*)(ws + 79691776);   //    262,144
  float* ls1 = (float*)(ws + 79953920);   //    262,144  (ends 80,216,064)

  prep_kernel<<<6400, 256, 0, stream>>>(x, xb, mask, mbits, wq, wk, wv, wo, wqkvT, woT);
  gemm2<<<dim3(64, 12), 256, 0, stream>>>(xb, wqkvT, 8192, 1536, 512, nullptr, qpre, kpre, vtb, 1);
  rope_pair_kernel<<<1024, 256, 0, stream>>>(qpre, kpre, cose, sine, qbh, kbh);
  flash_kernel<<<512, 512, 0, stream>>>(qbh, kbh, vtb, mbits, op0, op1, ls0, ls1);
  gemm_fused<<<dim3(128, 4), 256, 0, stream>>>(op0, op1, ls0, ls1, woT, out);
}